// Round 14
// baseline (220.016 us; speedup 1.0000x reference)
//
#include <hip/hip_runtime.h>
#include <hip/hip_bf16.h>
#include <math.h>

// PharmMatchNetFast — round 14: algebraic GEMM3/GEMM4 fusion in enc_p.
// g1raw = (y@proj)@gw1 = y@(proj*gw1): fuse_k precomputes C=proj*gw1 (bf16),
// enc_p computes hp and g1raw from the SAME y A-frags in one merged ks-loop.
// Removes 2 barriers + the hp->X LDS write pass; A-frag loads feed 4 MFMAs.
#define B_ 128
#define L_ 128
#define P_ 1024
#define D_ 128
#define NT_ 256

#define NEGF (-__FLT_MAX__)
#define SCALE_ 0.08838834764831845f
#define CLAMPV 1e30f

// output offsets (elements)
#define OUT_SHARP  16793600
#define OUT_NEGENT 16793728
#define OUT_LZ     16793856
#define OUT_PZ     16810240
#define OUT_SIG    16826624

// ws offsets (floats)
#define WS_HLB    0
#define WS_HPB    1048576
#define WS_DUST   9437184
#define WS_SHARPP 9453568
#define WS_ENTP   9454592
#define WS_FLAG   9455616
#define WS_WT     9455632
#define WS_PPART  9500696
#define WS_PCNT   10024984

using bh8  = __attribute__((ext_vector_type(8))) short;
using fx4  = __attribute__((ext_vector_type(4))) float;

__device__ __forceinline__ float gelu_(float x) {
    float c = x * x;
    float v = x * fmaf(c, 0.07135481584f, 1.5957691216f);
    return x * __builtin_amdgcn_rcpf(1.0f + __expf(-v));
}
__device__ __forceinline__ float bf2f(unsigned short u) {
    return __uint_as_float(((unsigned)u) << 16);
}
__device__ __forceinline__ float sanz(float x) {
    return fminf(fmaxf(x, -CLAMPV), CLAMPV);
}
template<int BF> __device__ __forceinline__ float ldf(const void* p, int i) {
    if constexpr (BF) return bf2f(((const unsigned short*)p)[i]);
    else return ((const float*)p)[i];
}
template<int BF> __device__ __forceinline__ void stf(void* p, size_t i, float x) {
    x = sanz(x);
    if constexpr (BF) ((__hip_bfloat16*)p)[i] = __float2bfloat16(x);
    else ((float*)p)[i] = x;
}
__device__ __forceinline__ float maskf(const void* m, int mm, int idx) {
    if (mm == 3) return ((const float*)m)[idx] != 0.f ? 1.f : 0.f;
    if (mm == 2) return ((const unsigned short*)m)[idx] ? 1.f : 0.f;
    if (mm == 1) return ((const unsigned char*)m)[idx] ? 1.f : 0.f;
    return ((const int*)m)[idx] ? 1.f : 0.f;
}
__device__ __forceinline__ int typf(const void* p, int tm, int idx) {
    int v;
    if (tm == 2) v = (int)bf2f(((const unsigned short*)p)[idx]);
    else if (tm == 1) v = (int)((const long long*)p)[idx];
    else v = ((const int*)p)[idx];
    return v < 0 ? 0 : (v > NT_ - 1 ? NT_ - 1 : v);
}

__global__ __launch_bounds__(64) void detect_k(const unsigned int* __restrict__ px,
                                               const unsigned int* __restrict__ pm,
                                               const unsigned int* __restrict__ pt,
                                               int* __restrict__ flags)
{
    const int t = threadIdx.x;
    int hit = 0;
    for (int i = t; i < 4096; i += 64) {
        unsigned e = (px[i] >> 7) & 0xFFu;
        hit += (e >= 110 && e <= 132) ? 1 : 0;
    }
    for (int s = 1; s < 64; s <<= 1) hit += __shfl_xor(hit, s);

    unsigned big = 0, lo3f = 0, hi3f = 0;
    for (int i = t; i < 1024; i += 64) {
        unsigned wv = pm[i];
        big  |= (wv > 1u) ? 1u : 0u;
        lo3f |= ((wv & 0xFFFFu) == 0x3F80u) ? 1u : 0u;
        hi3f |= ((wv >> 16) == 0x3F80u) ? 1u : 0u;
    }
    unsigned long long aBig = __ballot(big != 0), aLo = __ballot(lo3f != 0), aHi = __ballot(hi3f != 0);

    unsigned tbig = 0, oddnz = 0;
    for (int i = t; i < 512; i += 64) {
        unsigned we = pt[2 * i], wo = pt[2 * i + 1];
        tbig  |= (we > 0xFFFFu || wo > 0xFFFFu) ? 1u : 0u;
        oddnz |= (wo != 0u) ? 1u : 0u;
    }
    unsigned long long aTb = __ballot(tbig != 0), aOdd = __ballot(oddnz != 0);

    if (t == 0) {
        flags[1] = (hit > 2048) ? 1 : 0;
        flags[0] = aLo ? 2 : (aHi ? 3 : (aBig ? 1 : 0));
        flags[2] = aTb ? 2 : (!aOdd ? 1 : 0);
    }
}

// ---------------- weight transpose prep (w1T, w2cT, projT) ----------------
template<int BF> __device__ __forceinline__ void wt_prep_body(
    const void* w1, const void* w2, const void* sw2,
    const void* proj, __hip_bfloat16* wt)
{
    const int idx = blockIdx.x * 256 + threadIdx.x;
    const int stride = gridDim.x * 256;
    for (int i = idx; i < 128 * 192; i += stride) {
        int n = i / 192, k = i - n * 192;
        wt[n * 192 + k] = __float2bfloat16(ldf<BF>(w1, k * 128 + n));
    }
    __hip_bfloat16* w2c = wt + 24576;
    for (int i = idx; i < 128 * 256; i += stride) {
        int n = i >> 8, k = i & 255;
        float v = (k < 128) ? ldf<BF>(w2, k * 128 + n) : ldf<BF>(sw2, (k - 128) * 128 + n);
        w2c[n * 256 + k] = __float2bfloat16(v);
    }
    __hip_bfloat16* pjt = wt + 57344;
    for (int i = idx; i < 128 * 128; i += stride) {
        int n = i >> 7, k = i & 127;
        pjt[n * 128 + k] = __float2bfloat16(ldf<BF>(proj, k * 128 + n));
    }
}

__global__ __launch_bounds__(256) void wt_prep_k(
    const void* w1, const void* w2, const void* sw2,
    const void* proj, __hip_bfloat16* wt, const int* flags)
{
    if (flags[1]) wt_prep_body<1>(w1, w2, sw2, proj, wt);
    else          wt_prep_body<0>(w1, w2, sw2, proj, wt);
}

// ---------------- fused weight C = proj @ gw1 -> wt+73728 as C^T[n][k] ----------------
// C[k_out... ] : g1raw[:,n] = sum_k y[:,k]*C[n][k], C[n][k] = sum_d proj[k][d]*gw1[d][n].
// 4 lanes per entry (d split 4x32) + shfl reduce. 65536 threads.
__global__ __launch_bounds__(256) void fuse_k(const void* proj, const void* gw1,
                                              __hip_bfloat16* pg1, const int* flags)
{
    const int BF = flags[1];
    const int tid = blockIdx.x * 256 + threadIdx.x;
    const int e = tid >> 2, ll = tid & 3;
    const int n = e >> 7, k = e & 127;
    float s = 0.f;
    if (BF) {
        const unsigned short* pj = (const unsigned short*)proj + k * 128 + ll * 32;
        const unsigned short* g1 = (const unsigned short*)gw1;
#pragma unroll 8
        for (int d = 0; d < 32; d++)
            s = fmaf(bf2f(pj[d]), bf2f(g1[(ll * 32 + d) * 128 + n]), s);
    } else {
        const float* pj = (const float*)proj + k * 128 + ll * 32;
        const float* g1 = (const float*)gw1;
#pragma unroll 8
        for (int d = 0; d < 32; d++)
            s = fmaf(pj[d], g1[(ll * 32 + d) * 128 + n], s);
    }
    s += __shfl_xor(s, 1); s += __shfl_xor(s, 2);
    if (ll == 0) pg1[n * 128 + k] = __float2bfloat16(s);
}

// ---------------- encode L ----------------
#define RL 8
template<int BF> __device__ __forceinline__ void enc_l_body(
    const void* l_x, const void* l_typ, int tm,
    const void* w1, const void* b1, const void* w2, const void* b2,
    const void* lng, const void* lnb, const void* emb, const void* proj,
    const void* dustv, __hip_bfloat16* hLb, float* dust)
{
    __shared__ __align__(16) float X[RL * 8];
    __shared__ __align__(16) float H[RL][D_];
    __shared__ __align__(16) float Y[RL][D_];
    __shared__ float mus[RL], rss[RL];
    const int o = threadIdx.x;
    const int base = blockIdx.x * RL;

    if (o < RL * 8) X[o] = ldf<BF>(l_x, base * 8 + o);
    __syncthreads();

    float acc[RL];
    const float b1o = ldf<BF>(b1, o);
#pragma unroll
    for (int r = 0; r < RL; r++) acc[r] = b1o;
#pragma unroll
    for (int i = 0; i < 8; i += 4) {
        float wa = ldf<BF>(w1, (i + 0) * D_ + o), wb = ldf<BF>(w1, (i + 1) * D_ + o);
        float wc = ldf<BF>(w1, (i + 2) * D_ + o), wd = ldf<BF>(w1, (i + 3) * D_ + o);
#pragma unroll
        for (int r = 0; r < RL; r++) {
            const float4 x4 = *(const float4*)&X[r * 8 + i];
            acc[r] = fmaf(x4.x, wa, fmaf(x4.y, wb, fmaf(x4.z, wc, fmaf(x4.w, wd, acc[r]))));
        }
    }
#pragma unroll
    for (int r = 0; r < RL; r++) H[r][o] = gelu_(acc[r]);
    __syncthreads();

#pragma unroll
    for (int r = 0; r < RL; r++) {
        int tt = typf(l_typ, tm, base + r);
        acc[r] = ldf<BF>(b2, o) + ldf<BF>(emb, tt * D_ + o);
    }
    for (int i = 0; i < D_; i += 4) {
        float wa = ldf<BF>(w2, (i + 0) * D_ + o), wb = ldf<BF>(w2, (i + 1) * D_ + o);
        float wc = ldf<BF>(w2, (i + 2) * D_ + o), wd = ldf<BF>(w2, (i + 3) * D_ + o);
#pragma unroll
        for (int r = 0; r < RL; r++) {
            const float4 h4 = *(const float4*)&H[r][i];
            acc[r] = fmaf(h4.x, wa, fmaf(h4.y, wb, fmaf(h4.z, wc, fmaf(h4.w, wd, acc[r]))));
        }
    }
#pragma unroll
    for (int r = 0; r < RL; r++) Y[r][o] = acc[r];
    __syncthreads();

    {
        const int r = o >> 4, j = o & 15;
        float s = 0.f;
#pragma unroll
        for (int i = 0; i < 8; i++) s += Y[r][j * 8 + i];
        s += __shfl_xor(s, 1); s += __shfl_xor(s, 2); s += __shfl_xor(s, 4); s += __shfl_xor(s, 8);
        const float mu = s * (1.f / 128.f);
        float v = 0.f;
#pragma unroll
        for (int i = 0; i < 8; i++) { float d = Y[r][j * 8 + i] - mu; v = fmaf(d, d, v); }
        v += __shfl_xor(v, 1); v += __shfl_xor(v, 2); v += __shfl_xor(v, 4); v += __shfl_xor(v, 8);
        if (j == 0) { mus[r] = mu; rss[r] = rsqrtf(v * (1.f / 128.f) + 1e-5f); }
    }
    __syncthreads();
    {
        const float g = ldf<BF>(lng, o), bl = ldf<BF>(lnb, o);
#pragma unroll
        for (int r = 0; r < RL; r++) Y[r][o] = fmaf((Y[r][o] - mus[r]) * rss[r], g, bl);
    }
    __syncthreads();

#pragma unroll
    for (int r = 0; r < RL; r++) acc[r] = 0.f;
    for (int i = 0; i < D_; i += 4) {
        float wa = ldf<BF>(proj, (i + 0) * D_ + o), wb = ldf<BF>(proj, (i + 1) * D_ + o);
        float wc = ldf<BF>(proj, (i + 2) * D_ + o), wd = ldf<BF>(proj, (i + 3) * D_ + o);
#pragma unroll
        for (int r = 0; r < RL; r++) {
            const float4 y4 = *(const float4*)&Y[r][i];
            acc[r] = fmaf(y4.x, wa, fmaf(y4.y, wb, fmaf(y4.z, wc, fmaf(y4.w, wd, acc[r]))));
        }
    }
    const float dvo = ldf<BF>(dustv, o);
#pragma unroll
    for (int r = 0; r < RL; r++) {
        hLb[(size_t)(base + r) * D_ + o] = __float2bfloat16(acc[r]);
        H[r][o] = acc[r] * dvo;
    }
    __syncthreads();
    {
        const int r = o >> 4, j = o & 15;
        float s = 0.f;
#pragma unroll
        for (int i = 0; i < 8; i++) s += H[r][j * 8 + i];
        s += __shfl_xor(s, 1); s += __shfl_xor(s, 2); s += __shfl_xor(s, 4); s += __shfl_xor(s, 8);
        if (j == 0) dust[base + r] = s * SCALE_;
    }
}

__global__ __launch_bounds__(128) void enc_l_k(
    const void* l_x, const void* l_typ,
    const void* w1, const void* b1, const void* w2, const void* b2,
    const void* lng, const void* lnb, const void* emb, const void* proj,
    const void* dustv, __hip_bfloat16* hLb, float* dust, const int* flags)
{
    const int tm = flags[2];
    if (flags[1]) enc_l_body<1>(l_x, l_typ, tm, w1, b1, w2, b2, lng, lnb, emb, proj, dustv, hLb, dust);
    else          enc_l_body<0>(l_x, l_typ, tm, w1, b1, w2, b2, lng, lnb, emb, proj, dustv, hLb, dust);
}

// ---------------- encode P (MFMA, 64 rows, 256 thr, merged GEMM3+4) ----------------
#define XS 264
#define ROWS 64
#define ENC_P_SMEM 36608
template<int BF> __device__ __forceinline__ void enc_p_body(
    unsigned short* X, float* red1, float* red2, float* pm_s, float* sc_s, int* tt_s,
    const void* p_x, const void* p_typ, int tm,
    const void* p_score, const void* p_rad,
    const void* b1, const void* b2, const void* sb2,
    const void* sw1, const void* sb1,
    const void* lng, const void* lnb, const void* emb,
    const void* gb1, const void* gw2, const void* gb2,
    const unsigned short* wt, const void* p_mask, int mm,
    void* out, __hip_bfloat16* hPb, float* ppart, float* pcnt)
{
    const int t = threadIdx.x;
    const int o = t & 127, rh = t >> 7;
    const int lane = t & 63, w = t >> 6;
    const int m = lane & 15, g = lane >> 4;
    const int b = blockIdx.x >> 4, tile = blockIdx.x & 15;
    const int base = b * P_ + tile * ROWS;
    const int c0 = 32 * w + m, c1 = 32 * w + 16 + m;
    __hip_bfloat16* Xb = (__hip_bfloat16*)X;

    // stage p_x tile
    if constexpr (BF) {
        const unsigned short* src = (const unsigned short*)p_x + (size_t)base * 192;
#pragma unroll
        for (int i = t * 8; i < ROWS * 192; i += 256 * 8) {
            const int r = i / 192, k = i - r * 192;
            *(bh8*)(X + r * XS + k) = *(const bh8*)(src + i);
        }
    } else {
        for (int i = t; i < ROWS * 192; i += 256) {
            int r = i / 192, k = i - r * 192;
            Xb[r * XS + k] = __float2bfloat16(((const float*)p_x)[(size_t)base * 192 + i]);
        }
    }
    if (t < ROWS) {
        pm_s[t] = maskf(p_mask, mm, base + t);
        sc_s[t] = ldf<BF>(p_score, base + t);
        tt_s[t] = typf(p_typ, tm, base + t);
    }
    __syncthreads();

    // GEMM1: X[64x192] @ w1 (ks-outer)
    fx4 A1[4][2];
#pragma unroll
    for (int mt = 0; mt < 4; mt++) { A1[mt][0] = fx4{0,0,0,0}; A1[mt][1] = fx4{0,0,0,0}; }
    {
        const unsigned short* q0 = wt + ((2 * w + 0) * 16 + m) * 192 + g * 8;
        const unsigned short* q1 = wt + ((2 * w + 1) * 16 + m) * 192 + g * 8;
#pragma unroll
        for (int ks = 0; ks < 6; ks++) {
            bh8 f0 = *(const bh8*)(q0 + ks * 32);
            bh8 f1 = *(const bh8*)(q1 + ks * 32);
#pragma unroll
            for (int mt = 0; mt < 4; mt++) {
                bh8 a = *(const bh8*)(X + (mt * 16 + m) * XS + g * 8 + ks * 32);
                A1[mt][0] = __builtin_amdgcn_mfma_f32_16x16x32_bf16(a, f0, A1[mt][0], 0, 0, 0);
                A1[mt][1] = __builtin_amdgcn_mfma_f32_16x16x32_bf16(a, f1, A1[mt][1], 0, 0, 0);
            }
        }
    }
    __syncthreads();

    // ep1: h1 = gelu(D + b1) -> X[:,0:128]; hs -> X[:,128:256]
    {
        const float bb0 = ldf<BF>(b1, c0), bb1 = ldf<BF>(b1, c1);
#pragma unroll
        for (int mt = 0; mt < 4; mt++)
#pragma unroll
            for (int j = 0; j < 4; j++) {
                const int row = mt * 16 + g * 4 + j;
                Xb[row * XS + c0] = __float2bfloat16(gelu_(A1[mt][0][j] + bb0));
                Xb[row * XS + c1] = __float2bfloat16(gelu_(A1[mt][1][j] + bb1));
            }
    }
    {
        const float a1v = ldf<BF>(sw1, o), a0v = ldf<BF>(sb1, o);
#pragma unroll
        for (int r = 0; r < 32; r++) {
            const int row = rh * 32 + r;
            Xb[row * XS + 128 + o] = __float2bfloat16(gelu_(fmaf(sc_s[row], a1v, a0v)));
        }
    }
    __syncthreads();

    // GEMM2: [h1|hs][64x256] @ w2c
    fx4 A2[4][2];
#pragma unroll
    for (int mt = 0; mt < 4; mt++) { A2[mt][0] = fx4{0,0,0,0}; A2[mt][1] = fx4{0,0,0,0}; }
    {
        const unsigned short* w2cT = wt + 24576;
        const unsigned short* q0 = w2cT + ((2 * w + 0) * 16 + m) * 256 + g * 8;
        const unsigned short* q1 = w2cT + ((2 * w + 1) * 16 + m) * 256 + g * 8;
#pragma unroll
        for (int ks = 0; ks < 8; ks++) {
            bh8 f0 = *(const bh8*)(q0 + ks * 32);
            bh8 f1 = *(const bh8*)(q1 + ks * 32);
#pragma unroll
            for (int mt = 0; mt < 4; mt++) {
                bh8 a = *(const bh8*)(X + (mt * 16 + m) * XS + g * 8 + ks * 32);
                A2[mt][0] = __builtin_amdgcn_mfma_f32_16x16x32_bf16(a, f0, A2[mt][0], 0, 0, 0);
                A2[mt][1] = __builtin_amdgcn_mfma_f32_16x16x32_bf16(a, f1, A2[mt][1], 0, 0, 0);
            }
        }
    }
    // ep2: h2 = D + b2 + sb2 + emb[typ]
    {
        const float bc0 = ldf<BF>(b2, c0) + ldf<BF>(sb2, c0);
        const float bc1 = ldf<BF>(b2, c1) + ldf<BF>(sb2, c1);
#pragma unroll
        for (int mt = 0; mt < 4; mt++)
#pragma unroll
            for (int j = 0; j < 4; j++) {
                const int row = mt * 16 + g * 4 + j;
                const int tt = tt_s[row];
                A2[mt][0][j] += bc0 + ldf<BF>(emb, tt * D_ + c0);
                A2[mt][1][j] += bc1 + ldf<BF>(emb, tt * D_ + c1);
            }
    }
    // single-pass LN partials: sum + sumsq in one reduction round
#pragma unroll
    for (int mt = 0; mt < 4; mt++)
#pragma unroll
        for (int j = 0; j < 4; j++) {
            const int row = mt * 16 + g * 4 + j;
            float s = A2[mt][0][j] + A2[mt][1][j];
            float q = fmaf(A2[mt][0][j], A2[mt][0][j], A2[mt][1][j] * A2[mt][1][j]);
            s += __shfl_xor(s, 1); s += __shfl_xor(s, 2); s += __shfl_xor(s, 4); s += __shfl_xor(s, 8);
            q += __shfl_xor(q, 1); q += __shfl_xor(q, 2); q += __shfl_xor(q, 4); q += __shfl_xor(q, 8);
            if (m == 0) { red1[row * 4 + w] = s; red2[row * 4 + w] = q; }
        }
    __syncthreads();
    // LN apply -> X bf16
    {
        const float gc0 = ldf<BF>(lng, c0), bl0 = ldf<BF>(lnb, c0);
        const float gc1 = ldf<BF>(lng, c1), bl1 = ldf<BF>(lnb, c1);
#pragma unroll
        for (int mt = 0; mt < 4; mt++)
#pragma unroll
            for (int j = 0; j < 4; j++) {
                const int row = mt * 16 + g * 4 + j;
                float S = (red1[row * 4 + 0] + red1[row * 4 + 1]) + (red1[row * 4 + 2] + red1[row * 4 + 3]);
                float Q = (red2[row * 4 + 0] + red2[row * 4 + 1]) + (red2[row * 4 + 2] + red2[row * 4 + 3]);
                float mu = S * (1.f / 128.f);
                float var = fmaf(Q, 1.f / 128.f, -mu * mu);
                float rs = rsqrtf(var + 1e-5f);
                float y0 = fmaf((A2[mt][0][j] - mu) * rs, gc0, bl0);
                float y1 = fmaf((A2[mt][1][j] - mu) * rs, gc1, bl1);
                Xb[row * XS + c0] = __float2bfloat16(y0);
                Xb[row * XS + c1] = __float2bfloat16(y1);
            }
    }
    __syncthreads();

    // merged GEMM3+4: hp = y@proj, g1raw = y@C (C=proj*gw1); same A-frags
    fx4 A3[4][2], A4[4][2];
#pragma unroll
    for (int mt = 0; mt < 4; mt++) {
        A3[mt][0] = fx4{0,0,0,0}; A3[mt][1] = fx4{0,0,0,0};
        A4[mt][0] = fx4{0,0,0,0}; A4[mt][1] = fx4{0,0,0,0};
    }
    {
        const unsigned short* pjT = wt + 57344;
        const unsigned short* pg1 = wt + 73728;
        const unsigned short* q30 = pjT + ((2 * w + 0) * 16 + m) * 128 + g * 8;
        const unsigned short* q31 = pjT + ((2 * w + 1) * 16 + m) * 128 + g * 8;
        const unsigned short* q40 = pg1 + ((2 * w + 0) * 16 + m) * 128 + g * 8;
        const unsigned short* q41 = pg1 + ((2 * w + 1) * 16 + m) * 128 + g * 8;
#pragma unroll
        for (int ks = 0; ks < 4; ks++) {
            bh8 f30 = *(const bh8*)(q30 + ks * 32);
            bh8 f31 = *(const bh8*)(q31 + ks * 32);
            bh8 f40 = *(const bh8*)(q40 + ks * 32);
            bh8 f41 = *(const bh8*)(q41 + ks * 32);
#pragma unroll
            for (int mt = 0; mt < 4; mt++) {
                bh8 a = *(const bh8*)(X + (mt * 16 + m) * XS + g * 8 + ks * 32);
                A3[mt][0] = __builtin_amdgcn_mfma_f32_16x16x32_bf16(a, f30, A3[mt][0], 0, 0, 0);
                A3[mt][1] = __builtin_amdgcn_mfma_f32_16x16x32_bf16(a, f31, A3[mt][1], 0, 0, 0);
                A4[mt][0] = __builtin_amdgcn_mfma_f32_16x16x32_bf16(a, f40, A4[mt][0], 0, 0, 0);
                A4[mt][1] = __builtin_amdgcn_mfma_f32_16x16x32_bf16(a, f41, A4[mt][1], 0, 0, 0);
            }
        }
    }
    // X no longer used: no barrier needed.

    // ep3: hPb store + pool partials (register-only)
    {
#pragma unroll
        for (int mt = 0; mt < 4; mt++)
#pragma unroll
            for (int j = 0; j < 4; j++) {
                const int row = mt * 16 + g * 4 + j;
                hPb[(size_t)(base + row) * D_ + c0] = __float2bfloat16(A3[mt][0][j]);
                hPb[(size_t)(base + row) * D_ + c1] = __float2bfloat16(A3[mt][1][j]);
            }
        float ps0 = 0.f, ps1 = 0.f;
#pragma unroll
        for (int mt = 0; mt < 4; mt++)
#pragma unroll
            for (int j = 0; j < 4; j++) {
                const int row = mt * 16 + g * 4 + j;
                ps0 = fmaf(A3[mt][0][j], pm_s[row], ps0);
                ps1 = fmaf(A3[mt][1][j], pm_s[row], ps1);
            }
        ps0 += __shfl_xor(ps0, 16); ps0 += __shfl_xor(ps0, 32);
        ps1 += __shfl_xor(ps1, 16); ps1 += __shfl_xor(ps1, 32);
        if (g == 0) {
            ppart[(size_t)blockIdx.x * D_ + c0] = ps0;
            ppart[(size_t)blockIdx.x * D_ + c1] = ps1;
        }
        if (t == 0) {
            float c = 0.f;
#pragma unroll
            for (int r = 0; r < ROWS; r++) c += pm_s[r];
            pcnt[blockIdx.x] = c;
        }
    }

    // ep4: g1 = gelu(g1raw + gb1); sigma dot partials
    {
        const float gb0 = ldf<BF>(gb1, c0), gb1v = ldf<BF>(gb1, c1);
        const float w20 = ldf<BF>(gw2, c0), w21 = ldf<BF>(gw2, c1);
#pragma unroll
        for (int mt = 0; mt < 4; mt++)
#pragma unroll
            for (int j = 0; j < 4; j++) {
                const int row = mt * 16 + g * 4 + j;
                float g0 = gelu_(A4[mt][0][j] + gb0);
                float g1v = gelu_(A4[mt][1][j] + gb1v);
                float p = fmaf(g0, w20, g1v * w21);
                p += __shfl_xor(p, 1); p += __shfl_xor(p, 2); p += __shfl_xor(p, 4); p += __shfl_xor(p, 8);
                if (m == 0) red1[row * 4 + w] = p;
            }
    }
    __syncthreads();
    if (t < ROWS) {
        float s = (red1[t * 4 + 0] + red1[t * 4 + 1]) + (red1[t * 4 + 2] + red1[t * 4 + 3]);
        float v = s + ldf<BF>(gb2, 0);
        float sp = fmaxf(v, 0.f) + log1pf(expf(-fabsf(v)));
        stf<BF>(out, (size_t)OUT_SIG + base + t, sp + 1e-3f + fmaxf(ldf<BF>(p_rad, base + t), 0.f));
    }
}

__global__ __launch_bounds__(256) void enc_p_k(
    const void* p_x, const void* p_typ, const void* p_score, const void* p_rad,
    const void* b1, const void* b2, const void* sb2,
    const void* sw1, const void* sb1,
    const void* lng, const void* lnb, const void* emb,
    const void* gb1, const void* gw2, const void* gb2,
    const unsigned short* wt, const void* p_mask, const int* flags,
    void* out, __hip_bfloat16* hPb, float* ppart, float* pcnt)
{
    extern __shared__ __align__(16) char smem[];
    unsigned short* X = (unsigned short*)smem;          // 64*264*2 = 33792 B
    float* red1 = (float*)(smem + 33792);               // 1024 B
    float* red2 = (float*)(smem + 34816);               // 1024 B
    float* pm_s = (float*)(smem + 35840);               // 256 B
    float* sc_s = (float*)(smem + 36096);               // 256 B
    int*   tt_s = (int*)(smem + 36352);                 // 256 B
    const int tm = flags[2], mm = flags[0];
    if (flags[1]) enc_p_body<1>(X, red1, red2, pm_s, sc_s, tt_s,
                                p_x, p_typ, tm, p_score, p_rad, b1, b2, sb2, sw1, sb1,
                                lng, lnb, emb, gb1, gw2, gb2, wt, p_mask, mm,
                                out, hPb, ppart, pcnt);
    else          enc_p_body<0>(X, red1, red2, pm_s, sc_s, tt_s,
                                p_x, p_typ, tm, p_score, p_rad, b1, b2, sb2, sw1, sb1,
                                lng, lnb, emb, gb1, gw2, gb2, wt, p_mask, mm,
                                out, hPb, ppart, pcnt);
}

// ---------------- logits (MFMA) + fused softmax + sharp/ent ----------------
template<int BF> __device__ __forceinline__ void logits_sm_body(
    const unsigned short* hLb, const unsigned short* hPb, const float* dust,
    const void* l_mask, const void* p_mask, int mm,
    void* out, float* sharp_parts, float* ent_parts)
{
    __shared__ float pm_s[1024];
    __shared__ float lm_s[16], dv_s[16];
    __shared__ float redA[64], redB[64], redC[64], redD[64], redM[16], redL[16];
    const int t = threadIdx.x;
    const int lane = t & 63, w = t >> 6;
    const int m = lane & 15, g = lane >> 4;
    const int b = blockIdx.x & 127, l0 = (blockIdx.x >> 7) * 16;

    for (int i = t; i < 1024; i += 256) pm_s[i] = maskf(p_mask, mm, b * P_ + i);
    if (t < 16) {
        lm_s[t] = maskf(l_mask, mm, b * L_ + l0 + t);
        dv_s[t] = dust[b * L_ + l0 + t];
    }
    __syncthreads();

    bh8 af[4];
    {
        const unsigned short* ha = hLb + ((size_t)(b * L_ + l0 + m)) * D_ + g * 8;
#pragma unroll
        for (int ks = 0; ks < 4; ks++) af[ks] = *(const bh8*)(ha + ks * 32);
    }
    const unsigned short* hpb = hPb + ((size_t)(b * P_ + w * 256)) * D_;

    fx4 acc[16];
#pragma unroll
    for (int nt = 0; nt < 16; nt++) {
        fx4 c = {0.f, 0.f, 0.f, 0.f};
        const unsigned short* hr = hpb + (nt * 16 + m) * D_ + g * 8;
#pragma unroll
        for (int ks = 0; ks < 4; ks++) {
            bh8 bfr = *(const bh8*)(hr + ks * 32);
            c = __builtin_amdgcn_mfma_f32_16x16x32_bf16(af[ks], bfr, c, 0, 0, 0);
        }
        acc[nt] = c;
    }

    float rmax[4] = {NEGF, NEGF, NEGF, NEGF};
#pragma unroll
    for (int nt = 0; nt < 16; nt++) {
        const float pv = pm_s[w * 256 + nt * 16 + m];
#pragma unroll
        for (int j = 0; j < 4; j++) {
            const bool ok = (lm_s[g * 4 + j] != 0.f) && (pv != 0.f);
            float v = ok ? acc[nt][j] * SCALE_ : NEGF;
            acc[nt][j] = v;
            rmax[j] = fmaxf(rmax[j], v);
        }
    }
#pragma unroll
    for (int j = 0; j < 4; j++) {
        rmax[j] = fmaxf(rmax[j], __shfl_xor(rmax[j], 1));
        rmax[j] = fmaxf(rmax[j], __shfl_xor(rmax[j], 2));
        rmax[j] = fmaxf(rmax[j], __shfl_xor(rmax[j], 4));
        rmax[j] = fmaxf(rmax[j], __shfl_xor(rmax[j], 8));
    }
    if (m == 0) {
#pragma unroll
        for (int j = 0; j < 4; j++) redA[(g * 4 + j) * 4 + w] = rmax[j];
    }
    __syncthreads();
    float mrow[4], lse[4];
#pragma unroll
    for (int j = 0; j < 4; j++) {
        const int r = g * 4 + j;
        float mm4 = fmaxf(fmaxf(redA[r * 4 + 0], redA[r * 4 + 1]), fmaxf(redA[r * 4 + 2], redA[r * 4 + 3]));
        float dvr = (lm_s[r] != 0.f) ? dv_s[r] : NEGF;
        mrow[j] = fmaxf(mm4, dvr);
    }
    float se[4] = {0.f, 0.f, 0.f, 0.f};
#pragma unroll
    for (int nt = 0; nt < 16; nt++) {
#pragma unroll
        for (int j = 0; j < 4; j++) se[j] += __expf(acc[nt][j] - mrow[j]);
    }
#pragma unroll
    for (int j = 0; j < 4; j++) {
        se[j] += __shfl_xor(se[j], 1); se[j] += __shfl_xor(se[j], 2);
        se[j] += __shfl_xor(se[j], 4); se[j] += __shfl_xor(se[j], 8);
    }
    if (m == 0) {
#pragma unroll
        for (int j = 0; j < 4; j++) redB[(g * 4 + j) * 4 + w] = se[j];
    }
    __syncthreads();
#pragma unroll
    for (int j = 0; j < 4; j++) {
        const int r = g * 4 + j;
        float dvr = (lm_s[r] != 0.f) ? dv_s[r] : NEGF;
        float s = (redB[r * 4 + 0] + redB[r * 4 + 1]) + (redB[r * 4 + 2] + redB[r * 4 + 3]);
        s += __expf(dvr - mrow[j]);
        lse[j] = __logf(s);
    }
    if (w == 0 && m == 0) {
#pragma unroll
        for (int j = 0; j < 4; j++) { redM[g * 4 + j] = mrow[j]; redL[g * 4 + j] = lse[j]; }
    }
    float mw[4] = {0.f, 0.f, 0.f, 0.f}, es[4] = {0.f, 0.f, 0.f, 0.f};
#pragma unroll
    for (int nt = 0; nt < 16; nt++) {
        const float pv = pm_s[w * 256 + nt * 16 + m];
#pragma unroll
        for (int j = 0; j < 4; j++) {
            float lw = acc[nt][j] - mrow[j] - lse[j];
            stf<BF>(out, (size_t)(b * L_ + l0 + g * 4 + j) * (P_ + 1) + w * 256 + nt * 16 + m, lw);
            float lwc = fmaxf(lw, -CLAMPV);
            float wm = __expf(lwc) * pv;
            mw[j] = fmaxf(mw[j], wm);
            if (wm > 0.f) es[j] = fmaf(-wm, lwc, es[j]);
        }
    }
#pragma unroll
    for (int j = 0; j < 4; j++) {
        mw[j] = fmaxf(mw[j], __shfl_xor(mw[j], 1));
        mw[j] = fmaxf(mw[j], __shfl_xor(mw[j], 2));
        mw[j] = fmaxf(mw[j], __shfl_xor(mw[j], 4));
        mw[j] = fmaxf(mw[j], __shfl_xor(mw[j], 8));
        es[j] += __shfl_xor(es[j], 1); es[j] += __shfl_xor(es[j], 2);
        es[j] += __shfl_xor(es[j], 4); es[j] += __shfl_xor(es[j], 8);
    }
    if (m == 0) {
#pragma unroll
        for (int j = 0; j < 4; j++) {
            redC[(g * 4 + j) * 4 + w] = mw[j];
            redD[(g * 4 + j) * 4 + w] = es[j];
        }
    }
    __syncthreads();
    if (t < 16) {
        float dvr = (lm_s[t] != 0.f) ? dv_s[t] : NEGF;
        stf<BF>(out, (size_t)(b * L_ + l0 + t) * (P_ + 1) + P_, dvr - redM[t] - redL[t]);
    }
    if (t == 0) {
        float sp = 0.f, en = 0.f;
        for (int r = 0; r < 16; r++) {
            float dvr = (lm_s[r] != 0.f) ? dv_s[r] : NEGF;
            float lwd = fmaxf(dvr - redM[r] - redL[r], -CLAMPV);
            float wd = __expf(lwd);
            float mwr = fmaxf(fmaxf(redC[r * 4 + 0], redC[r * 4 + 1]), fmaxf(redC[r * 4 + 2], redC[r * 4 + 3]));
            mwr = fmaxf(mwr, wd);
            float esr = (redD[r * 4 + 0] + redD[r * 4 + 1]) + (redD[r * 4 + 2] + redD[r * 4 + 3]);
            if (wd > 0.f) esr = fmaf(-wd, lwd, esr);
            sp = fmaf(mwr, lm_s[r], sp);
            en = fmaf(esr, lm_s[r], en);
        }
        sharp_parts[blockIdx.x] = sp;
        ent_parts[blockIdx.x] = en;
    }
}

__global__ __launch_bounds__(256) void logits_sm_k(
    const unsigned short* hLb, const unsigned short* hPb, const float* dust,
    const void* l_mask, const void* p_mask, const int* flags,
    void* out, float* sharp_parts, float* ent_parts)
{
    const int mm = flags[0];
    if (flags[1]) logits_sm_body<1>(hLb, hPb, dust, l_mask, p_mask, mm, out, sharp_parts, ent_parts);
    else          logits_sm_body<0>(hLb, hPb, dust, l_mask, p_mask, mm, out, sharp_parts, ent_parts);
}

// ---------------- epilogue: pool_l + pool_p + finalize ----------------
template<int BF> __device__ __forceinline__ void epilogue_body(
    const unsigned short* hLb, const void* l_mask, int mm,
    const void* retr_l, const void* retr_p,
    const float* ppart, const float* pcnt,
    const float* sharp_parts, const float* ent_parts, void* out)
{
    __shared__ float lmv[L_];
    __shared__ __align__(16) float lg[D_];
    __shared__ __align__(16) float pgs[D_];
    __shared__ float red[4];
    const int o = threadIdx.x, b = blockIdx.x;
    lmv[o] = maskf(l_mask, mm, b * L_ + o);
    __syncthreads();
    float cnt = 0.f;
    for (int l = 0; l < L_; l++) cnt += lmv[l];
    {
        float s0 = 0, s1 = 0, s2 = 0, s3 = 0;
        const unsigned short* hb = hLb + (size_t)b * L_ * D_;
        for (int l = 0; l < L_; l += 4) {
            s0 = fmaf(bf2f(hb[(l + 0) * D_ + o]), lmv[l + 0], s0);
            s1 = fmaf(bf2f(hb[(l + 1) * D_ + o]), lmv[l + 1], s1);
            s2 = fmaf(bf2f(hb[(l + 2) * D_ + o]), lmv[l + 2], s2);
            s3 = fmaf(bf2f(hb[(l + 3) * D_ + o]), lmv[l + 3], s3);
        }
        lg[o] = ((s0 + s1) + (s2 + s3)) / fmaxf(cnt, 1.f);
    }
    {
        float s = 0.f, c = 0.f;
        for (int k = 0; k < 16; k++) s += ppart[(size_t)(b * 16 + k) * D_ + o];
        for (int k = 0; k < 16; k++) c += pcnt[b * 16 + k];
        pgs[o] = s / fmaxf(c, 1.f);
    }
    __syncthreads();
    float rL = 0.f, rP = 0.f;
    for (int i = 0; i < D_; i += 4) {
        const float4 g4 = *(const float4*)&lg[i];
        rL = fmaf(g4.x, ldf<BF>(retr_l, (i + 0) * D_ + o), rL);
        rL = fmaf(g4.y, ldf<BF>(retr_l, (i + 1) * D_ + o), rL);
        rL = fmaf(g4.z, ldf<BF>(retr_l, (i + 2) * D_ + o), rL);
        rL = fmaf(g4.w, ldf<BF>(retr_l, (i + 3) * D_ + o), rL);
        const float4 p4 = *(const float4*)&pgs[i];
        rP = fmaf(p4.x, ldf<BF>(retr_p, (i + 0) * D_ + o), rP);
        rP = fmaf(p4.y, ldf<BF>(retr_p, (i + 1) * D_ + o), rP);
        rP = fmaf(p4.z, ldf<BF>(retr_p, (i + 2) * D_ + o), rP);
        rP = fmaf(p4.w, ldf<BF>(retr_p, (i + 3) * D_ + o), rP);
    }
    float nL = rL * rL, nP = rP * rP;
    nL += __shfl_xor(nL, 1); nL += __shfl_xor(nL, 2); nL += __shfl_xor(nL, 4);
    nL += __shfl_xor(nL, 8); nL += __shfl_xor(nL, 16); nL += __shfl_xor(nL, 32);
    nP += __shfl_xor(nP, 1); nP += __shfl_xor(nP, 2); nP += __shfl_xor(nP, 4);
    nP += __shfl_xor(nP, 8); nP += __shfl_xor(nP, 16); nP += __shfl_xor(nP, 32);
    if ((o & 63) == 0) { red[o >> 6] = nL; red[2 + (o >> 6)] = nP; }
    __syncthreads();
    {
        float nrmL = fmaxf(sqrtf(red[0] + red[1]), 1e-12f);
        float nrmP = fmaxf(sqrtf(red[2] + red[3]), 1e-12f);
        stf<BF>(out, (size_t)OUT_LZ + b * D_ + o, rL / nrmL);
        stf<BF>(out, (size_t)OUT_PZ + b * D_ + o, rP / nrmP);
    }
    if (o == 0) {
        const float den = fmaxf(cnt, 1.f);
        float sp = 0.f, en = 0.f;
        for (int k = 0; k < 8; k++) { sp += sharp_parts[k * 128 + b]; en += ent_parts[k * 128 + b]; }
        stf<BF>(out, (size_t)OUT_SHARP + b, sp / den);
        stf<BF>(out, (size_t)OUT_NEGENT + b, -(en / den));
    }
}

__global__ __launch_bounds__(128) void epilogue_k(
    const unsigned short* hLb, const void* l_mask, const int* flags,
    const void* retr_l, const void* retr_p,
    const float* ppart, const float* pcnt,
    const float* sharp_parts, const float* ent_parts, void* out)
{
    const int mm = flags[0];
    if (flags[1]) epilogue_body<1>(hLb, l_mask, mm, retr_l, retr_p, ppart, pcnt, sharp_parts, ent_parts, out);
    else          epilogue_body<0>(hLb, l_mask, mm, retr_l, retr_p, ppart, pcnt, sharp_parts, ent_parts, out);
}

extern "C" void kernel_launch(void* const* d_in, const int* in_sizes, int n_in,
                              void* d_out, int out_size, void* d_ws, size_t ws_size,
                              hipStream_t stream)
{
    const void* l_x     = d_in[0];
    const void* l_typ   = d_in[1];
    const void* p_x     = d_in[2];
    const void* p_typ   = d_in[3];
    const void* p_score = d_in[4];
    const void* p_rad   = d_in[5];
    const void* l_mask  = d_in[6];
    const void* p_mask  = d_in[7];
    const void* lt_emb  = d_in[8];
    const void* lx_w1   = d_in[9];
    const void* lx_b1   = d_in[10];
    const void* lx_w2   = d_in[11];
    const void* lx_b2   = d_in[12];
    const void* l_ln_g  = d_in[13];
    const void* l_ln_b  = d_in[14];
    const void* pt_emb  = d_in[15];
    const void* px_w1   = d_in[16];
    const void* px_b1   = d_in[17];
    const void* px_w2   = d_in[18];
    const void* px_b2   = d_in[19];
    const void* ps_w1   = d_in[20];
    const void* ps_b1   = d_in[21];
    const void* ps_w2   = d_in[22];
    const void* ps_b2   = d_in[23];
    const void* p_ln_g  = d_in[24];
    const void* p_ln_b  = d_in[25];
    const void* proj_l  = d_in[26];
    const void* proj_p  = d_in[27];
    const void* dustv   = d_in[28];
    const void* sg_w1   = d_in[29];
    const void* sg_b1   = d_in[30];
    const void* sg_w2   = d_in[31];
    const void* sg_b2   = d_in[32];
    const void* retr_l  = d_in[33];
    const void* retr_p  = d_in[34];

    float* ws     = (float*)d_ws;
    __hip_bfloat16* hLb = (__hip_bfloat16*)(ws + WS_HLB);
    __hip_bfloat16* hPb = (__hip_bfloat16*)(ws + WS_HPB);
    float* dust   = ws + WS_DUST;
    float* sharpp = ws + WS_SHARPP;
    float* entp   = ws + WS_ENTP;
    int*   flags  = (int*)(ws + WS_FLAG);
    __hip_bfloat16* wt = (__hip_bfloat16*)(ws + WS_WT);
    float* ppart  = ws + WS_PPART;
    float* pcnt   = ws + WS_PCNT;

    detect_k<<<1, 64, 0, stream>>>((const unsigned int*)p_x, (const unsigned int*)p_mask,
                                   (const unsigned int*)p_typ, flags);
    wt_prep_k<<<64, 256, 0, stream>>>(px_w1, px_w2, ps_w2, proj_p, wt, flags);
    fuse_k<<<256, 256, 0, stream>>>(proj_p, sg_w1, wt + 73728, flags);
    enc_l_k<<<(B_ * L_) / RL, 128, 0, stream>>>(l_x, l_typ, lx_w1, lx_b1, lx_w2, lx_b2,
                                                l_ln_g, l_ln_b, lt_emb, proj_l, dustv,
                                                hLb, dust, flags);
    enc_p_k<<<B_ * (P_ / ROWS), 256, ENC_P_SMEM, stream>>>(
        p_x, p_typ, p_score, p_rad,
        px_b1, px_b2, ps_b2, ps_w1, ps_b1,
        p_ln_g, p_ln_b, pt_emb,
        sg_b1, sg_w2, sg_b2,
        (const unsigned short*)wt, p_mask, flags,
        d_out, hPb, ppart, pcnt);
    logits_sm_k<<<B_ * 8, 256, 0, stream>>>((const unsigned short*)hLb, (const unsigned short*)hPb,
                                            dust, l_mask, p_mask, flags, d_out, sharpp, entp);
    epilogue_k<<<B_, 128, 0, stream>>>((const unsigned short*)hLb, l_mask, flags,
                                       retr_l, retr_p, ppart, pcnt, sharpp, entp, d_out);
}

// Round 15
// 218.964 us; speedup vs baseline: 1.0048x; 1.0048x over previous
//
#include <hip/hip_runtime.h>
#include <hip/hip_bf16.h>
#include <math.h>

// PharmMatchNetFast — round 15: R14's algebraic fusion (C=proj*gw1) kept, but
// GEMM3 and GEMM4 run SEQUENTIALLY over the same resident y tile (R14's
// interleave held A3+A4 live together -> VGPR 100, occupancy 21.6%, net
// regression). A3 dies before A4 lives -> VGPR ~72, R13 occupancy, and still
// 2 fewer barriers + no hp->X write vs R13.
#define B_ 128
#define L_ 128
#define P_ 1024
#define D_ 128
#define NT_ 256

#define NEGF (-__FLT_MAX__)
#define SCALE_ 0.08838834764831845f
#define CLAMPV 1e30f

// output offsets (elements)
#define OUT_SHARP  16793600
#define OUT_NEGENT 16793728
#define OUT_LZ     16793856
#define OUT_PZ     16810240
#define OUT_SIG    16826624

// ws offsets (floats)
#define WS_HLB    0
#define WS_HPB    1048576
#define WS_DUST   9437184
#define WS_SHARPP 9453568
#define WS_ENTP   9454592
#define WS_FLAG   9455616
#define WS_WT     9455632
#define WS_PPART  9500696
#define WS_PCNT   10024984

using bh8  = __attribute__((ext_vector_type(8))) short;
using fx4  = __attribute__((ext_vector_type(4))) float;

__device__ __forceinline__ float gelu_(float x) {
    float c = x * x;
    float v = x * fmaf(c, 0.07135481584f, 1.5957691216f);
    return x * __builtin_amdgcn_rcpf(1.0f + __expf(-v));
}
__device__ __forceinline__ float bf2f(unsigned short u) {
    return __uint_as_float(((unsigned)u) << 16);
}
__device__ __forceinline__ float sanz(float x) {
    return fminf(fmaxf(x, -CLAMPV), CLAMPV);
}
template<int BF> __device__ __forceinline__ float ldf(const void* p, int i) {
    if constexpr (BF) return bf2f(((const unsigned short*)p)[i]);
    else return ((const float*)p)[i];
}
template<int BF> __device__ __forceinline__ void stf(void* p, size_t i, float x) {
    x = sanz(x);
    if constexpr (BF) ((__hip_bfloat16*)p)[i] = __float2bfloat16(x);
    else ((float*)p)[i] = x;
}
__device__ __forceinline__ float maskf(const void* m, int mm, int idx) {
    if (mm == 3) return ((const float*)m)[idx] != 0.f ? 1.f : 0.f;
    if (mm == 2) return ((const unsigned short*)m)[idx] ? 1.f : 0.f;
    if (mm == 1) return ((const unsigned char*)m)[idx] ? 1.f : 0.f;
    return ((const int*)m)[idx] ? 1.f : 0.f;
}
__device__ __forceinline__ int typf(const void* p, int tm, int idx) {
    int v;
    if (tm == 2) v = (int)bf2f(((const unsigned short*)p)[idx]);
    else if (tm == 1) v = (int)((const long long*)p)[idx];
    else v = ((const int*)p)[idx];
    return v < 0 ? 0 : (v > NT_ - 1 ? NT_ - 1 : v);
}

__global__ __launch_bounds__(64) void detect_k(const unsigned int* __restrict__ px,
                                               const unsigned int* __restrict__ pm,
                                               const unsigned int* __restrict__ pt,
                                               int* __restrict__ flags)
{
    const int t = threadIdx.x;
    int hit = 0;
    for (int i = t; i < 4096; i += 64) {
        unsigned e = (px[i] >> 7) & 0xFFu;
        hit += (e >= 110 && e <= 132) ? 1 : 0;
    }
    for (int s = 1; s < 64; s <<= 1) hit += __shfl_xor(hit, s);

    unsigned big = 0, lo3f = 0, hi3f = 0;
    for (int i = t; i < 1024; i += 64) {
        unsigned wv = pm[i];
        big  |= (wv > 1u) ? 1u : 0u;
        lo3f |= ((wv & 0xFFFFu) == 0x3F80u) ? 1u : 0u;
        hi3f |= ((wv >> 16) == 0x3F80u) ? 1u : 0u;
    }
    unsigned long long aBig = __ballot(big != 0), aLo = __ballot(lo3f != 0), aHi = __ballot(hi3f != 0);

    unsigned tbig = 0, oddnz = 0;
    for (int i = t; i < 512; i += 64) {
        unsigned we = pt[2 * i], wo = pt[2 * i + 1];
        tbig  |= (we > 0xFFFFu || wo > 0xFFFFu) ? 1u : 0u;
        oddnz |= (wo != 0u) ? 1u : 0u;
    }
    unsigned long long aTb = __ballot(tbig != 0), aOdd = __ballot(oddnz != 0);

    if (t == 0) {
        flags[1] = (hit > 2048) ? 1 : 0;
        flags[0] = aLo ? 2 : (aHi ? 3 : (aBig ? 1 : 0));
        flags[2] = aTb ? 2 : (!aOdd ? 1 : 0);
    }
}

// ---------------- weight transpose prep (w1T, w2cT, projT) ----------------
template<int BF> __device__ __forceinline__ void wt_prep_body(
    const void* w1, const void* w2, const void* sw2,
    const void* proj, __hip_bfloat16* wt)
{
    const int idx = blockIdx.x * 256 + threadIdx.x;
    const int stride = gridDim.x * 256;
    for (int i = idx; i < 128 * 192; i += stride) {
        int n = i / 192, k = i - n * 192;
        wt[n * 192 + k] = __float2bfloat16(ldf<BF>(w1, k * 128 + n));
    }
    __hip_bfloat16* w2c = wt + 24576;
    for (int i = idx; i < 128 * 256; i += stride) {
        int n = i >> 8, k = i & 255;
        float v = (k < 128) ? ldf<BF>(w2, k * 128 + n) : ldf<BF>(sw2, (k - 128) * 128 + n);
        w2c[n * 256 + k] = __float2bfloat16(v);
    }
    __hip_bfloat16* pjt = wt + 57344;
    for (int i = idx; i < 128 * 128; i += stride) {
        int n = i >> 7, k = i & 127;
        pjt[n * 128 + k] = __float2bfloat16(ldf<BF>(proj, k * 128 + n));
    }
}

__global__ __launch_bounds__(256) void wt_prep_k(
    const void* w1, const void* w2, const void* sw2,
    const void* proj, __hip_bfloat16* wt, const int* flags)
{
    if (flags[1]) wt_prep_body<1>(w1, w2, sw2, proj, wt);
    else          wt_prep_body<0>(w1, w2, sw2, proj, wt);
}

// ---------------- fused weight C = proj @ gw1 -> wt+73728 as C^T[n][k] ----------------
__global__ __launch_bounds__(256) void fuse_k(const void* proj, const void* gw1,
                                              __hip_bfloat16* pg1, const int* flags)
{
    const int BF = flags[1];
    const int tid = blockIdx.x * 256 + threadIdx.x;
    const int e = tid >> 2, ll = tid & 3;
    const int n = e >> 7, k = e & 127;
    float s = 0.f;
    if (BF) {
        const unsigned short* pj = (const unsigned short*)proj + k * 128 + ll * 32;
        const unsigned short* g1 = (const unsigned short*)gw1;
#pragma unroll 8
        for (int d = 0; d < 32; d++)
            s = fmaf(bf2f(pj[d]), bf2f(g1[(ll * 32 + d) * 128 + n]), s);
    } else {
        const float* pj = (const float*)proj + k * 128 + ll * 32;
        const float* g1 = (const float*)gw1;
#pragma unroll 8
        for (int d = 0; d < 32; d++)
            s = fmaf(pj[d], g1[(ll * 32 + d) * 128 + n], s);
    }
    s += __shfl_xor(s, 1); s += __shfl_xor(s, 2);
    if (ll == 0) pg1[n * 128 + k] = __float2bfloat16(s);
}

// ---------------- encode L ----------------
#define RL 8
template<int BF> __device__ __forceinline__ void enc_l_body(
    const void* l_x, const void* l_typ, int tm,
    const void* w1, const void* b1, const void* w2, const void* b2,
    const void* lng, const void* lnb, const void* emb, const void* proj,
    const void* dustv, __hip_bfloat16* hLb, float* dust)
{
    __shared__ __align__(16) float X[RL * 8];
    __shared__ __align__(16) float H[RL][D_];
    __shared__ __align__(16) float Y[RL][D_];
    __shared__ float mus[RL], rss[RL];
    const int o = threadIdx.x;
    const int base = blockIdx.x * RL;

    if (o < RL * 8) X[o] = ldf<BF>(l_x, base * 8 + o);
    __syncthreads();

    float acc[RL];
    const float b1o = ldf<BF>(b1, o);
#pragma unroll
    for (int r = 0; r < RL; r++) acc[r] = b1o;
#pragma unroll
    for (int i = 0; i < 8; i += 4) {
        float wa = ldf<BF>(w1, (i + 0) * D_ + o), wb = ldf<BF>(w1, (i + 1) * D_ + o);
        float wc = ldf<BF>(w1, (i + 2) * D_ + o), wd = ldf<BF>(w1, (i + 3) * D_ + o);
#pragma unroll
        for (int r = 0; r < RL; r++) {
            const float4 x4 = *(const float4*)&X[r * 8 + i];
            acc[r] = fmaf(x4.x, wa, fmaf(x4.y, wb, fmaf(x4.z, wc, fmaf(x4.w, wd, acc[r]))));
        }
    }
#pragma unroll
    for (int r = 0; r < RL; r++) H[r][o] = gelu_(acc[r]);
    __syncthreads();

#pragma unroll
    for (int r = 0; r < RL; r++) {
        int tt = typf(l_typ, tm, base + r);
        acc[r] = ldf<BF>(b2, o) + ldf<BF>(emb, tt * D_ + o);
    }
    for (int i = 0; i < D_; i += 4) {
        float wa = ldf<BF>(w2, (i + 0) * D_ + o), wb = ldf<BF>(w2, (i + 1) * D_ + o);
        float wc = ldf<BF>(w2, (i + 2) * D_ + o), wd = ldf<BF>(w2, (i + 3) * D_ + o);
#pragma unroll
        for (int r = 0; r < RL; r++) {
            const float4 h4 = *(const float4*)&H[r][i];
            acc[r] = fmaf(h4.x, wa, fmaf(h4.y, wb, fmaf(h4.z, wc, fmaf(h4.w, wd, acc[r]))));
        }
    }
#pragma unroll
    for (int r = 0; r < RL; r++) Y[r][o] = acc[r];
    __syncthreads();

    {
        const int r = o >> 4, j = o & 15;
        float s = 0.f;
#pragma unroll
        for (int i = 0; i < 8; i++) s += Y[r][j * 8 + i];
        s += __shfl_xor(s, 1); s += __shfl_xor(s, 2); s += __shfl_xor(s, 4); s += __shfl_xor(s, 8);
        const float mu = s * (1.f / 128.f);
        float v = 0.f;
#pragma unroll
        for (int i = 0; i < 8; i++) { float d = Y[r][j * 8 + i] - mu; v = fmaf(d, d, v); }
        v += __shfl_xor(v, 1); v += __shfl_xor(v, 2); v += __shfl_xor(v, 4); v += __shfl_xor(v, 8);
        if (j == 0) { mus[r] = mu; rss[r] = rsqrtf(v * (1.f / 128.f) + 1e-5f); }
    }
    __syncthreads();
    {
        const float g = ldf<BF>(lng, o), bl = ldf<BF>(lnb, o);
#pragma unroll
        for (int r = 0; r < RL; r++) Y[r][o] = fmaf((Y[r][o] - mus[r]) * rss[r], g, bl);
    }
    __syncthreads();

#pragma unroll
    for (int r = 0; r < RL; r++) acc[r] = 0.f;
    for (int i = 0; i < D_; i += 4) {
        float wa = ldf<BF>(proj, (i + 0) * D_ + o), wb = ldf<BF>(proj, (i + 1) * D_ + o);
        float wc = ldf<BF>(proj, (i + 2) * D_ + o), wd = ldf<BF>(proj, (i + 3) * D_ + o);
#pragma unroll
        for (int r = 0; r < RL; r++) {
            const float4 y4 = *(const float4*)&Y[r][i];
            acc[r] = fmaf(y4.x, wa, fmaf(y4.y, wb, fmaf(y4.z, wc, fmaf(y4.w, wd, acc[r]))));
        }
    }
    const float dvo = ldf<BF>(dustv, o);
#pragma unroll
    for (int r = 0; r < RL; r++) {
        hLb[(size_t)(base + r) * D_ + o] = __float2bfloat16(acc[r]);
        H[r][o] = acc[r] * dvo;
    }
    __syncthreads();
    {
        const int r = o >> 4, j = o & 15;
        float s = 0.f;
#pragma unroll
        for (int i = 0; i < 8; i++) s += H[r][j * 8 + i];
        s += __shfl_xor(s, 1); s += __shfl_xor(s, 2); s += __shfl_xor(s, 4); s += __shfl_xor(s, 8);
        if (j == 0) dust[base + r] = s * SCALE_;
    }
}

__global__ __launch_bounds__(128) void enc_l_k(
    const void* l_x, const void* l_typ,
    const void* w1, const void* b1, const void* w2, const void* b2,
    const void* lng, const void* lnb, const void* emb, const void* proj,
    const void* dustv, __hip_bfloat16* hLb, float* dust, const int* flags)
{
    const int tm = flags[2];
    if (flags[1]) enc_l_body<1>(l_x, l_typ, tm, w1, b1, w2, b2, lng, lnb, emb, proj, dustv, hLb, dust);
    else          enc_l_body<0>(l_x, l_typ, tm, w1, b1, w2, b2, lng, lnb, emb, proj, dustv, hLb, dust);
}

// ---------------- encode P (MFMA, 64 rows, 256 thr, sequential GEMM3 then GEMM4) ----------------
#define XS 264
#define ROWS 64
#define ENC_P_SMEM 36608
template<int BF> __device__ __forceinline__ void enc_p_body(
    unsigned short* X, float* red1, float* red2, float* pm_s, float* sc_s, int* tt_s,
    const void* p_x, const void* p_typ, int tm,
    const void* p_score, const void* p_rad,
    const void* b1, const void* b2, const void* sb2,
    const void* sw1, const void* sb1,
    const void* lng, const void* lnb, const void* emb,
    const void* gb1, const void* gw2, const void* gb2,
    const unsigned short* wt, const void* p_mask, int mm,
    void* out, __hip_bfloat16* hPb, float* ppart, float* pcnt)
{
    const int t = threadIdx.x;
    const int o = t & 127, rh = t >> 7;
    const int lane = t & 63, w = t >> 6;
    const int m = lane & 15, g = lane >> 4;
    const int b = blockIdx.x >> 4, tile = blockIdx.x & 15;
    const int base = b * P_ + tile * ROWS;
    const int c0 = 32 * w + m, c1 = 32 * w + 16 + m;
    __hip_bfloat16* Xb = (__hip_bfloat16*)X;

    // stage p_x tile
    if constexpr (BF) {
        const unsigned short* src = (const unsigned short*)p_x + (size_t)base * 192;
#pragma unroll
        for (int i = t * 8; i < ROWS * 192; i += 256 * 8) {
            const int r = i / 192, k = i - r * 192;
            *(bh8*)(X + r * XS + k) = *(const bh8*)(src + i);
        }
    } else {
        for (int i = t; i < ROWS * 192; i += 256) {
            int r = i / 192, k = i - r * 192;
            Xb[r * XS + k] = __float2bfloat16(((const float*)p_x)[(size_t)base * 192 + i]);
        }
    }
    if (t < ROWS) {
        pm_s[t] = maskf(p_mask, mm, base + t);
        sc_s[t] = ldf<BF>(p_score, base + t);
        tt_s[t] = typf(p_typ, tm, base + t);
    }
    __syncthreads();

    // GEMM1: X[64x192] @ w1 (ks-outer)
    fx4 A1[4][2];
#pragma unroll
    for (int mt = 0; mt < 4; mt++) { A1[mt][0] = fx4{0,0,0,0}; A1[mt][1] = fx4{0,0,0,0}; }
    {
        const unsigned short* q0 = wt + ((2 * w + 0) * 16 + m) * 192 + g * 8;
        const unsigned short* q1 = wt + ((2 * w + 1) * 16 + m) * 192 + g * 8;
#pragma unroll
        for (int ks = 0; ks < 6; ks++) {
            bh8 f0 = *(const bh8*)(q0 + ks * 32);
            bh8 f1 = *(const bh8*)(q1 + ks * 32);
#pragma unroll
            for (int mt = 0; mt < 4; mt++) {
                bh8 a = *(const bh8*)(X + (mt * 16 + m) * XS + g * 8 + ks * 32);
                A1[mt][0] = __builtin_amdgcn_mfma_f32_16x16x32_bf16(a, f0, A1[mt][0], 0, 0, 0);
                A1[mt][1] = __builtin_amdgcn_mfma_f32_16x16x32_bf16(a, f1, A1[mt][1], 0, 0, 0);
            }
        }
    }
    __syncthreads();

    // ep1: h1 = gelu(D + b1) -> X[:,0:128]; hs -> X[:,128:256]
    {
        const float bb0 = ldf<BF>(b1, c0), bb1 = ldf<BF>(b1, c1);
#pragma unroll
        for (int mt = 0; mt < 4; mt++)
#pragma unroll
            for (int j = 0; j < 4; j++) {
                const int row = mt * 16 + g * 4 + j;
                Xb[row * XS + c0] = __float2bfloat16(gelu_(A1[mt][0][j] + bb0));
                Xb[row * XS + c1] = __float2bfloat16(gelu_(A1[mt][1][j] + bb1));
            }
    }
    {
        const float a1v = ldf<BF>(sw1, o), a0v = ldf<BF>(sb1, o);
#pragma unroll
        for (int r = 0; r < 32; r++) {
            const int row = rh * 32 + r;
            Xb[row * XS + 128 + o] = __float2bfloat16(gelu_(fmaf(sc_s[row], a1v, a0v)));
        }
    }
    __syncthreads();

    // GEMM2: [h1|hs][64x256] @ w2c
    fx4 A2[4][2];
#pragma unroll
    for (int mt = 0; mt < 4; mt++) { A2[mt][0] = fx4{0,0,0,0}; A2[mt][1] = fx4{0,0,0,0}; }
    {
        const unsigned short* w2cT = wt + 24576;
        const unsigned short* q0 = w2cT + ((2 * w + 0) * 16 + m) * 256 + g * 8;
        const unsigned short* q1 = w2cT + ((2 * w + 1) * 16 + m) * 256 + g * 8;
#pragma unroll
        for (int ks = 0; ks < 8; ks++) {
            bh8 f0 = *(const bh8*)(q0 + ks * 32);
            bh8 f1 = *(const bh8*)(q1 + ks * 32);
#pragma unroll
            for (int mt = 0; mt < 4; mt++) {
                bh8 a = *(const bh8*)(X + (mt * 16 + m) * XS + g * 8 + ks * 32);
                A2[mt][0] = __builtin_amdgcn_mfma_f32_16x16x32_bf16(a, f0, A2[mt][0], 0, 0, 0);
                A2[mt][1] = __builtin_amdgcn_mfma_f32_16x16x32_bf16(a, f1, A2[mt][1], 0, 0, 0);
            }
        }
    }
    // ep2: h2 = D + b2 + sb2 + emb[typ]
    {
        const float bc0 = ldf<BF>(b2, c0) + ldf<BF>(sb2, c0);
        const float bc1 = ldf<BF>(b2, c1) + ldf<BF>(sb2, c1);
#pragma unroll
        for (int mt = 0; mt < 4; mt++)
#pragma unroll
            for (int j = 0; j < 4; j++) {
                const int row = mt * 16 + g * 4 + j;
                const int tt = tt_s[row];
                A2[mt][0][j] += bc0 + ldf<BF>(emb, tt * D_ + c0);
                A2[mt][1][j] += bc1 + ldf<BF>(emb, tt * D_ + c1);
            }
    }
    // single-pass LN partials
#pragma unroll
    for (int mt = 0; mt < 4; mt++)
#pragma unroll
        for (int j = 0; j < 4; j++) {
            const int row = mt * 16 + g * 4 + j;
            float s = A2[mt][0][j] + A2[mt][1][j];
            float q = fmaf(A2[mt][0][j], A2[mt][0][j], A2[mt][1][j] * A2[mt][1][j]);
            s += __shfl_xor(s, 1); s += __shfl_xor(s, 2); s += __shfl_xor(s, 4); s += __shfl_xor(s, 8);
            q += __shfl_xor(q, 1); q += __shfl_xor(q, 2); q += __shfl_xor(q, 4); q += __shfl_xor(q, 8);
            if (m == 0) { red1[row * 4 + w] = s; red2[row * 4 + w] = q; }
        }
    __syncthreads();
    // LN apply -> X bf16
    {
        const float gc0 = ldf<BF>(lng, c0), bl0 = ldf<BF>(lnb, c0);
        const float gc1 = ldf<BF>(lng, c1), bl1 = ldf<BF>(lnb, c1);
#pragma unroll
        for (int mt = 0; mt < 4; mt++)
#pragma unroll
            for (int j = 0; j < 4; j++) {
                const int row = mt * 16 + g * 4 + j;
                float S = (red1[row * 4 + 0] + red1[row * 4 + 1]) + (red1[row * 4 + 2] + red1[row * 4 + 3]);
                float Q = (red2[row * 4 + 0] + red2[row * 4 + 1]) + (red2[row * 4 + 2] + red2[row * 4 + 3]);
                float mu = S * (1.f / 128.f);
                float var = fmaf(Q, 1.f / 128.f, -mu * mu);
                float rs = rsqrtf(var + 1e-5f);
                float y0 = fmaf((A2[mt][0][j] - mu) * rs, gc0, bl0);
                float y1 = fmaf((A2[mt][1][j] - mu) * rs, gc1, bl1);
                Xb[row * XS + c0] = __float2bfloat16(y0);
                Xb[row * XS + c1] = __float2bfloat16(y1);
            }
    }
    __syncthreads();

    // GEMM3: hp = y[64x128] @ proj   (A3 consumed by ep3 before A4 exists)
    {
        fx4 A3[4][2];
#pragma unroll
        for (int mt = 0; mt < 4; mt++) { A3[mt][0] = fx4{0,0,0,0}; A3[mt][1] = fx4{0,0,0,0}; }
        const unsigned short* pjT = wt + 57344;
        const unsigned short* q0 = pjT + ((2 * w + 0) * 16 + m) * 128 + g * 8;
        const unsigned short* q1 = pjT + ((2 * w + 1) * 16 + m) * 128 + g * 8;
#pragma unroll
        for (int ks = 0; ks < 4; ks++) {
            bh8 f0 = *(const bh8*)(q0 + ks * 32);
            bh8 f1 = *(const bh8*)(q1 + ks * 32);
#pragma unroll
            for (int mt = 0; mt < 4; mt++) {
                bh8 a = *(const bh8*)(X + (mt * 16 + m) * XS + g * 8 + ks * 32);
                A3[mt][0] = __builtin_amdgcn_mfma_f32_16x16x32_bf16(a, f0, A3[mt][0], 0, 0, 0);
                A3[mt][1] = __builtin_amdgcn_mfma_f32_16x16x32_bf16(a, f1, A3[mt][1], 0, 0, 0);
            }
        }
        // ep3: hPb store + pool partials (X untouched -> no barrier)
#pragma unroll
        for (int mt = 0; mt < 4; mt++)
#pragma unroll
            for (int j = 0; j < 4; j++) {
                const int row = mt * 16 + g * 4 + j;
                hPb[(size_t)(base + row) * D_ + c0] = __float2bfloat16(A3[mt][0][j]);
                hPb[(size_t)(base + row) * D_ + c1] = __float2bfloat16(A3[mt][1][j]);
            }
        float ps0 = 0.f, ps1 = 0.f;
#pragma unroll
        for (int mt = 0; mt < 4; mt++)
#pragma unroll
            for (int j = 0; j < 4; j++) {
                const int row = mt * 16 + g * 4 + j;
                ps0 = fmaf(A3[mt][0][j], pm_s[row], ps0);
                ps1 = fmaf(A3[mt][1][j], pm_s[row], ps1);
            }
        ps0 += __shfl_xor(ps0, 16); ps0 += __shfl_xor(ps0, 32);
        ps1 += __shfl_xor(ps1, 16); ps1 += __shfl_xor(ps1, 32);
        if (g == 0) {
            ppart[(size_t)blockIdx.x * D_ + c0] = ps0;
            ppart[(size_t)blockIdx.x * D_ + c1] = ps1;
        }
        if (t == 0) {
            float c = 0.f;
#pragma unroll
            for (int r = 0; r < ROWS; r++) c += pm_s[r];
            pcnt[blockIdx.x] = c;
        }
    }

    // GEMM4: g1raw = y[64x128] @ C (C = proj*gw1; y still resident in X)
    {
        fx4 A4[4][2];
#pragma unroll
        for (int mt = 0; mt < 4; mt++) { A4[mt][0] = fx4{0,0,0,0}; A4[mt][1] = fx4{0,0,0,0}; }
        const unsigned short* pg1 = wt + 73728;
        const unsigned short* q0 = pg1 + ((2 * w + 0) * 16 + m) * 128 + g * 8;
        const unsigned short* q1 = pg1 + ((2 * w + 1) * 16 + m) * 128 + g * 8;
#pragma unroll
        for (int ks = 0; ks < 4; ks++) {
            bh8 f0 = *(const bh8*)(q0 + ks * 32);
            bh8 f1 = *(const bh8*)(q1 + ks * 32);
#pragma unroll
            for (int mt = 0; mt < 4; mt++) {
                bh8 a = *(const bh8*)(X + (mt * 16 + m) * XS + g * 8 + ks * 32);
                A4[mt][0] = __builtin_amdgcn_mfma_f32_16x16x32_bf16(a, f0, A4[mt][0], 0, 0, 0);
                A4[mt][1] = __builtin_amdgcn_mfma_f32_16x16x32_bf16(a, f1, A4[mt][1], 0, 0, 0);
            }
        }
        // ep4: g1 = gelu(g1raw + gb1); sigma dot partials
        const float gb0 = ldf<BF>(gb1, c0), gb1v = ldf<BF>(gb1, c1);
        const float w20 = ldf<BF>(gw2, c0), w21 = ldf<BF>(gw2, c1);
#pragma unroll
        for (int mt = 0; mt < 4; mt++)
#pragma unroll
            for (int j = 0; j < 4; j++) {
                const int row = mt * 16 + g * 4 + j;
                float g0 = gelu_(A4[mt][0][j] + gb0);
                float g1v = gelu_(A4[mt][1][j] + gb1v);
                float p = fmaf(g0, w20, g1v * w21);
                p += __shfl_xor(p, 1); p += __shfl_xor(p, 2); p += __shfl_xor(p, 4); p += __shfl_xor(p, 8);
                if (m == 0) red1[row * 4 + w] = p;
            }
    }
    __syncthreads();
    if (t < ROWS) {
        float s = (red1[t * 4 + 0] + red1[t * 4 + 1]) + (red1[t * 4 + 2] + red1[t * 4 + 3]);
        float v = s + ldf<BF>(gb2, 0);
        float sp = fmaxf(v, 0.f) + log1pf(expf(-fabsf(v)));
        stf<BF>(out, (size_t)OUT_SIG + base + t, sp + 1e-3f + fmaxf(ldf<BF>(p_rad, base + t), 0.f));
    }
}

__global__ __launch_bounds__(256) void enc_p_k(
    const void* p_x, const void* p_typ, const void* p_score, const void* p_rad,
    const void* b1, const void* b2, const void* sb2,
    const void* sw1, const void* sb1,
    const void* lng, const void* lnb, const void* emb,
    const void* gb1, const void* gw2, const void* gb2,
    const unsigned short* wt, const void* p_mask, const int* flags,
    void* out, __hip_bfloat16* hPb, float* ppart, float* pcnt)
{
    extern __shared__ __align__(16) char smem[];
    unsigned short* X = (unsigned short*)smem;          // 64*264*2 = 33792 B
    float* red1 = (float*)(smem + 33792);               // 1024 B
    float* red2 = (float*)(smem + 34816);               // 1024 B
    float* pm_s = (float*)(smem + 35840);               // 256 B
    float* sc_s = (float*)(smem + 36096);               // 256 B
    int*   tt_s = (int*)(smem + 36352);                 // 256 B
    const int tm = flags[2], mm = flags[0];
    if (flags[1]) enc_p_body<1>(X, red1, red2, pm_s, sc_s, tt_s,
                                p_x, p_typ, tm, p_score, p_rad, b1, b2, sb2, sw1, sb1,
                                lng, lnb, emb, gb1, gw2, gb2, wt, p_mask, mm,
                                out, hPb, ppart, pcnt);
    else          enc_p_body<0>(X, red1, red2, pm_s, sc_s, tt_s,
                                p_x, p_typ, tm, p_score, p_rad, b1, b2, sb2, sw1, sb1,
                                lng, lnb, emb, gb1, gw2, gb2, wt, p_mask, mm,
                                out, hPb, ppart, pcnt);
}

// ---------------- logits (MFMA) + fused softmax + sharp/ent ----------------
template<int BF> __device__ __forceinline__ void logits_sm_body(
    const unsigned short* hLb, const unsigned short* hPb, const float* dust,
    const void* l_mask, const void* p_mask, int mm,
    void* out, float* sharp_parts, float* ent_parts)
{
    __shared__ float pm_s[1024];
    __shared__ float lm_s[16], dv_s[16];
    __shared__ float redA[64], redB[64], redC[64], redD[64], redM[16], redL[16];
    const int t = threadIdx.x;
    const int lane = t & 63, w = t >> 6;
    const int m = lane & 15, g = lane >> 4;
    const int b = blockIdx.x & 127, l0 = (blockIdx.x >> 7) * 16;

    for (int i = t; i < 1024; i += 256) pm_s[i] = maskf(p_mask, mm, b * P_ + i);
    if (t < 16) {
        lm_s[t] = maskf(l_mask, mm, b * L_ + l0 + t);
        dv_s[t] = dust[b * L_ + l0 + t];
    }
    __syncthreads();

    bh8 af[4];
    {
        const unsigned short* ha = hLb + ((size_t)(b * L_ + l0 + m)) * D_ + g * 8;
#pragma unroll
        for (int ks = 0; ks < 4; ks++) af[ks] = *(const bh8*)(ha + ks * 32);
    }
    const unsigned short* hpb = hPb + ((size_t)(b * P_ + w * 256)) * D_;

    fx4 acc[16];
#pragma unroll
    for (int nt = 0; nt < 16; nt++) {
        fx4 c = {0.f, 0.f, 0.f, 0.f};
        const unsigned short* hr = hpb + (nt * 16 + m) * D_ + g * 8;
#pragma unroll
        for (int ks = 0; ks < 4; ks++) {
            bh8 bfr = *(const bh8*)(hr + ks * 32);
            c = __builtin_amdgcn_mfma_f32_16x16x32_bf16(af[ks], bfr, c, 0, 0, 0);
        }
        acc[nt] = c;
    }

    float rmax[4] = {NEGF, NEGF, NEGF, NEGF};
#pragma unroll
    for (int nt = 0; nt < 16; nt++) {
        const float pv = pm_s[w * 256 + nt * 16 + m];
#pragma unroll
        for (int j = 0; j < 4; j++) {
            const bool ok = (lm_s[g * 4 + j] != 0.f) && (pv != 0.f);
            float v = ok ? acc[nt][j] * SCALE_ : NEGF;
            acc[nt][j] = v;
            rmax[j] = fmaxf(rmax[j], v);
        }
    }
#pragma unroll
    for (int j = 0; j < 4; j++) {
        rmax[j] = fmaxf(rmax[j], __shfl_xor(rmax[j], 1));
        rmax[j] = fmaxf(rmax[j], __shfl_xor(rmax[j], 2));
        rmax[j] = fmaxf(rmax[j], __shfl_xor(rmax[j], 4));
        rmax[j] = fmaxf(rmax[j], __shfl_xor(rmax[j], 8));
    }
    if (m == 0) {
#pragma unroll
        for (int j = 0; j < 4; j++) redA[(g * 4 + j) * 4 + w] = rmax[j];
    }
    __syncthreads();
    float mrow[4], lse[4];
#pragma unroll
    for (int j = 0; j < 4; j++) {
        const int r = g * 4 + j;
        float mm4 = fmaxf(fmaxf(redA[r * 4 + 0], redA[r * 4 + 1]), fmaxf(redA[r * 4 + 2], redA[r * 4 + 3]));
        float dvr = (lm_s[r] != 0.f) ? dv_s[r] : NEGF;
        mrow[j] = fmaxf(mm4, dvr);
    }
    float se[4] = {0.f, 0.f, 0.f, 0.f};
#pragma unroll
    for (int nt = 0; nt < 16; nt++) {
#pragma unroll
        for (int j = 0; j < 4; j++) se[j] += __expf(acc[nt][j] - mrow[j]);
    }
#pragma unroll
    for (int j = 0; j < 4; j++) {
        se[j] += __shfl_xor(se[j], 1); se[j] += __shfl_xor(se[j], 2);
        se[j] += __shfl_xor(se[j], 4); se[j] += __shfl_xor(se[j], 8);
    }
    if (m == 0) {
#pragma unroll
        for (int j = 0; j < 4; j++) redB[(g * 4 + j) * 4 + w] = se[j];
    }
    __syncthreads();
#pragma unroll
    for (int j = 0; j < 4; j++) {
        const int r = g * 4 + j;
        float dvr = (lm_s[r] != 0.f) ? dv_s[r] : NEGF;
        float s = (redB[r * 4 + 0] + redB[r * 4 + 1]) + (redB[r * 4 + 2] + redB[r * 4 + 3]);
        s += __expf(dvr - mrow[j]);
        lse[j] = __logf(s);
    }
    if (w == 0 && m == 0) {
#pragma unroll
        for (int j = 0; j < 4; j++) { redM[g * 4 + j] = mrow[j]; redL[g * 4 + j] = lse[j]; }
    }
    float mw[4] = {0.f, 0.f, 0.f, 0.f}, es[4] = {0.f, 0.f, 0.f, 0.f};
#pragma unroll
    for (int nt = 0; nt < 16; nt++) {
        const float pv = pm_s[w * 256 + nt * 16 + m];
#pragma unroll
        for (int j = 0; j < 4; j++) {
            float lw = acc[nt][j] - mrow[j] - lse[j];
            stf<BF>(out, (size_t)(b * L_ + l0 + g * 4 + j) * (P_ + 1) + w * 256 + nt * 16 + m, lw);
            float lwc = fmaxf(lw, -CLAMPV);
            float wm = __expf(lwc) * pv;
            mw[j] = fmaxf(mw[j], wm);
            if (wm > 0.f) es[j] = fmaf(-wm, lwc, es[j]);
        }
    }
#pragma unroll
    for (int j = 0; j < 4; j++) {
        mw[j] = fmaxf(mw[j], __shfl_xor(mw[j], 1));
        mw[j] = fmaxf(mw[j], __shfl_xor(mw[j], 2));
        mw[j] = fmaxf(mw[j], __shfl_xor(mw[j], 4));
        mw[j] = fmaxf(mw[j], __shfl_xor(mw[j], 8));
        es[j] += __shfl_xor(es[j], 1); es[j] += __shfl_xor(es[j], 2);
        es[j] += __shfl_xor(es[j], 4); es[j] += __shfl_xor(es[j], 8);
    }
    if (m == 0) {
#pragma unroll
        for (int j = 0; j < 4; j++) {
            redC[(g * 4 + j) * 4 + w] = mw[j];
            redD[(g * 4 + j) * 4 + w] = es[j];
        }
    }
    __syncthreads();
    if (t < 16) {
        float dvr = (lm_s[t] != 0.f) ? dv_s[t] : NEGF;
        stf<BF>(out, (size_t)(b * L_ + l0 + t) * (P_ + 1) + P_, dvr - redM[t] - redL[t]);
    }
    if (t == 0) {
        float sp = 0.f, en = 0.f;
        for (int r = 0; r < 16; r++) {
            float dvr = (lm_s[r] != 0.f) ? dv_s[r] : NEGF;
            float lwd = fmaxf(dvr - redM[r] - redL[r], -CLAMPV);
            float wd = __expf(lwd);
            float mwr = fmaxf(fmaxf(redC[r * 4 + 0], redC[r * 4 + 1]), fmaxf(redC[r * 4 + 2], redC[r * 4 + 3]));
            mwr = fmaxf(mwr, wd);
            float esr = (redD[r * 4 + 0] + redD[r * 4 + 1]) + (redD[r * 4 + 2] + redD[r * 4 + 3]);
            if (wd > 0.f) esr = fmaf(-wd, lwd, esr);
            sp = fmaf(mwr, lm_s[r], sp);
            en = fmaf(esr, lm_s[r], en);
        }
        sharp_parts[blockIdx.x] = sp;
        ent_parts[blockIdx.x] = en;
    }
}

__global__ __launch_bounds__(256) void logits_sm_k(
    const unsigned short* hLb, const unsigned short* hPb, const float* dust,
    const void* l_mask, const void* p_mask, const int* flags,
    void* out, float* sharp_parts, float* ent_parts)
{
    const int mm = flags[0];
    if (flags[1]) logits_sm_body<1>(hLb, hPb, dust, l_mask, p_mask, mm, out, sharp_parts, ent_parts);
    else          logits_sm_body<0>(hLb, hPb, dust, l_mask, p_mask, mm, out, sharp_parts, ent_parts);
}

// ---------------- epilogue: pool_l + pool_p + finalize ----------------
template<int BF> __device__ __forceinline__ void epilogue_body(
    const unsigned short* hLb, const void* l_mask, int mm,
    const void* retr_l, const void* retr_p,
    const float* ppart, const float* pcnt,
    const float* sharp_parts, const float* ent_parts, void* out)
{
    __shared__ float lmv[L_];
    __shared__ __align__(16) float lg[D_];
    __shared__ __align__(16) float pgs[D_];
    __shared__ float red[4];
    const int o = threadIdx.x, b = blockIdx.x;
    lmv[o] = maskf(l_mask, mm, b * L_ + o);
    __syncthreads();
    float cnt = 0.f;
    for (int l = 0; l < L_; l++) cnt += lmv[l];
    {
        float s0 = 0, s1 = 0, s2 = 0, s3 = 0;
        const unsigned short* hb = hLb + (size_t)b * L_ * D_;
        for (int l = 0; l < L_; l += 4) {
            s0 = fmaf(bf2f(hb[(l + 0) * D_ + o]), lmv[l + 0], s0);
            s1 = fmaf(bf2f(hb[(l + 1) * D_ + o]), lmv[l + 1], s1);
            s2 = fmaf(bf2f(hb[(l + 2) * D_ + o]), lmv[l + 2], s2);
            s3 = fmaf(bf2f(hb[(l + 3) * D_ + o]), lmv[l + 3], s3);
        }
        lg[o] = ((s0 + s1) + (s2 + s3)) / fmaxf(cnt, 1.f);
    }
    {
        float s = 0.f, c = 0.f;
        for (int k = 0; k < 16; k++) s += ppart[(size_t)(b * 16 + k) * D_ + o];
        for (int k = 0; k < 16; k++) c += pcnt[b * 16 + k];
        pgs[o] = s / fmaxf(c, 1.f);
    }
    __syncthreads();
    float rL = 0.f, rP = 0.f;
    for (int i = 0; i < D_; i += 4) {
        const float4 g4 = *(const float4*)&lg[i];
        rL = fmaf(g4.x, ldf<BF>(retr_l, (i + 0) * D_ + o), rL);
        rL = fmaf(g4.y, ldf<BF>(retr_l, (i + 1) * D_ + o), rL);
        rL = fmaf(g4.z, ldf<BF>(retr_l, (i + 2) * D_ + o), rL);
        rL = fmaf(g4.w, ldf<BF>(retr_l, (i + 3) * D_ + o), rL);
        const float4 p4 = *(const float4*)&pgs[i];
        rP = fmaf(p4.x, ldf<BF>(retr_p, (i + 0) * D_ + o), rP);
        rP = fmaf(p4.y, ldf<BF>(retr_p, (i + 1) * D_ + o), rP);
        rP = fmaf(p4.z, ldf<BF>(retr_p, (i + 2) * D_ + o), rP);
        rP = fmaf(p4.w, ldf<BF>(retr_p, (i + 3) * D_ + o), rP);
    }
    float nL = rL * rL, nP = rP * rP;
    nL += __shfl_xor(nL, 1); nL += __shfl_xor(nL, 2); nL += __shfl_xor(nL, 4);
    nL += __shfl_xor(nL, 8); nL += __shfl_xor(nL, 16); nL += __shfl_xor(nL, 32);
    nP += __shfl_xor(nP, 1); nP += __shfl_xor(nP, 2); nP += __shfl_xor(nP, 4);
    nP += __shfl_xor(nP, 8); nP += __shfl_xor(nP, 16); nP += __shfl_xor(nP, 32);
    if ((o & 63) == 0) { red[o >> 6] = nL; red[2 + (o >> 6)] = nP; }
    __syncthreads();
    {
        float nrmL = fmaxf(sqrtf(red[0] + red[1]), 1e-12f);
        float nrmP = fmaxf(sqrtf(red[2] + red[3]), 1e-12f);
        stf<BF>(out, (size_t)OUT_LZ + b * D_ + o, rL / nrmL);
        stf<BF>(out, (size_t)OUT_PZ + b * D_ + o, rP / nrmP);
    }
    if (o == 0) {
        const float den = fmaxf(cnt, 1.f);
        float sp = 0.f, en = 0.f;
        for (int k = 0; k < 8; k++) { sp += sharp_parts[k * 128 + b]; en += ent_parts[k * 128 + b]; }
        stf<BF>(out, (size_t)OUT_SHARP + b, sp / den);
        stf<BF>(out, (size_t)OUT_NEGENT + b, -(en / den));
    }
}

__global__ __launch_bounds__(128) void epilogue_k(
    const unsigned short* hLb, const void* l_mask, const int* flags,
    const void* retr_l, const void* retr_p,
    const float* ppart, const float* pcnt,
    const float* sharp_parts, const float* ent_parts, void* out)
{
    const int mm = flags[0];
    if (flags[1]) epilogue_body<1>(hLb, l_mask, mm, retr_l, retr_p, ppart, pcnt, sharp_parts, ent_parts, out);
    else          epilogue_body<0>(hLb, l_mask, mm, retr_l, retr_p, ppart, pcnt, sharp_parts, ent_parts, out);
}

extern "C" void kernel_launch(void* const* d_in, const int* in_sizes, int n_in,
                              void* d_out, int out_size, void* d_ws, size_t ws_size,
                              hipStream_t stream)
{
    const void* l_x     = d_in[0];
    const void* l_typ   = d_in[1];
    const void* p_x     = d_in[2];
    const void* p_typ   = d_in[3];
    const void* p_score = d_in[4];
    const void* p_rad   = d_in[5];
    const void* l_mask  = d_in[6];
    const void* p_mask  = d_in[7];
    const void* lt_emb  = d_in[8];
    const void* lx_w1   = d_in[9];
    const void* lx_b1   = d_in[10];
    const void* lx_w2   = d_in[11];
    const void* lx_b2   = d_in[12];
    const void* l_ln_g  = d_in[13];
    const void* l_ln_b  = d_in[14];
    const void* pt_emb  = d_in[15];
    const void* px_w1   = d_in[16];
    const void* px_b1   = d_in[17];
    const void* px_w2   = d_in[18];
    const void* px_b2   = d_in[19];
    const void* ps_w1   = d_in[20];
    const void* ps_b1   = d_in[21];
    const void* ps_w2   = d_in[22];
    const void* ps_b2   = d_in[23];
    const void* p_ln_g  = d_in[24];
    const void* p_ln_b  = d_in[25];
    const void* proj_l  = d_in[26];
    const void* proj_p  = d_in[27];
    const void* dustv   = d_in[28];
    const void* sg_w1   = d_in[29];
    const void* sg_b1   = d_in[30];
    const void* sg_w2   = d_in[31];
    const void* sg_b2   = d_in[32];
    const void* retr_l  = d_in[33];
    const void* retr_p  = d_in[34];

    float* ws     = (float*)d_ws;
    __hip_bfloat16* hLb = (__hip_bfloat16*)(ws + WS_HLB);
    __hip_bfloat16* hPb = (__hip_bfloat16*)(ws + WS_HPB);
    float* dust   = ws + WS_DUST;
    float* sharpp = ws + WS_SHARPP;
    float* entp   = ws + WS_ENTP;
    int*   flags  = (int*)(ws + WS_FLAG);
    __hip_bfloat16* wt = (__hip_bfloat16*)(ws + WS_WT);
    float* ppart  = ws + WS_PPART;
    float* pcnt   = ws + WS_PCNT;

    detect_k<<<1, 64, 0, stream>>>((const unsigned int*)p_x, (const unsigned int*)p_mask,
                                   (const unsigned int*)p_typ, flags);
    wt_prep_k<<<64, 256, 0, stream>>>(px_w1, px_w2, ps_w2, proj_p, wt, flags);
    fuse_k<<<256, 256, 0, stream>>>(proj_p, sg_w1, wt + 73728, flags);
    enc_l_k<<<(B_ * L_) / RL, 128, 0, stream>>>(l_x, l_typ, lx_w1, lx_b1, lx_w2, lx_b2,
                                                l_ln_g, l_ln_b, lt_emb, proj_l, dustv,
                                                hLb, dust, flags);
    enc_p_k<<<B_ * (P_ / ROWS), 256, ENC_P_SMEM, stream>>>(
        p_x, p_typ, p_score, p_rad,
        px_b1, px_b2, ps_b2, ps_w1, ps_b1,
        p_ln_g, p_ln_b, pt_emb,
        sg_b1, sg_w2, sg_b2,
        (const unsigned short*)wt, p_mask, flags,
        d_out, hPb, ppart, pcnt);
    logits_sm_k<<<B_ * 8, 256, 0, stream>>>((const unsigned short*)hLb, (const unsigned short*)hPb,
                                            dust, l_mask, p_mask, flags, d_out, sharpp, entp);
    epilogue_k<<<B_, 128, 0, stream>>>((const unsigned short*)hLb, l_mask, flags,
                                       retr_l, retr_p, ppart, pcnt, sharpp, entp, d_out);
}

// Round 16
// 203.534 us; speedup vs baseline: 1.0810x; 1.0758x over previous
//
#include <hip/hip_runtime.h>
#include <hip/hip_bf16.h>
#include <math.h>

// PharmMatchNetFast — round 16: REVERT to R13 verbatim (best: 204.0 µs).
// R14 (interleaved fusion, VGPR 100) and R15 (sequential fusion, VGPR 88)
// both lost more to the occupancy cliff than the barrier savings gained.
// R13: enc_p 256thr/4 waves/64 rows, single-pass LN, VGPR 72, occ 29%.
#define B_ 128
#define L_ 128
#define P_ 1024
#define D_ 128
#define NT_ 256

#define NEGF (-__FLT_MAX__)
#define SCALE_ 0.08838834764831845f
#define CLAMPV 1e30f

// output offsets (elements)
#define OUT_SHARP  16793600
#define OUT_NEGENT 16793728
#define OUT_LZ     16793856
#define OUT_PZ     16810240
#define OUT_SIG    16826624

// ws offsets (floats)
#define WS_HLB    0
#define WS_HPB    1048576
#define WS_DUST   9437184
#define WS_SHARPP 9453568
#define WS_ENTP   9454592
#define WS_FLAG   9455616
#define WS_WT     9455632
#define WS_PPART  9500696
#define WS_PCNT   10024984

using bh8  = __attribute__((ext_vector_type(8))) short;
using fx4  = __attribute__((ext_vector_type(4))) float;

__device__ __forceinline__ float gelu_(float x) {
    float c = x * x;
    float v = x * fmaf(c, 0.07135481584f, 1.5957691216f);
    return x * __builtin_amdgcn_rcpf(1.0f + __expf(-v));
}
__device__ __forceinline__ float bf2f(unsigned short u) {
    return __uint_as_float(((unsigned)u) << 16);
}
__device__ __forceinline__ float sanz(float x) {
    return fminf(fmaxf(x, -CLAMPV), CLAMPV);
}
template<int BF> __device__ __forceinline__ float ldf(const void* p, int i) {
    if constexpr (BF) return bf2f(((const unsigned short*)p)[i]);
    else return ((const float*)p)[i];
}
template<int BF> __device__ __forceinline__ void stf(void* p, size_t i, float x) {
    x = sanz(x);
    if constexpr (BF) ((__hip_bfloat16*)p)[i] = __float2bfloat16(x);
    else ((float*)p)[i] = x;
}
__device__ __forceinline__ float maskf(const void* m, int mm, int idx) {
    if (mm == 3) return ((const float*)m)[idx] != 0.f ? 1.f : 0.f;
    if (mm == 2) return ((const unsigned short*)m)[idx] ? 1.f : 0.f;
    if (mm == 1) return ((const unsigned char*)m)[idx] ? 1.f : 0.f;
    return ((const int*)m)[idx] ? 1.f : 0.f;
}
__device__ __forceinline__ int typf(const void* p, int tm, int idx) {
    int v;
    if (tm == 2) v = (int)bf2f(((const unsigned short*)p)[idx]);
    else if (tm == 1) v = (int)((const long long*)p)[idx];
    else v = ((const int*)p)[idx];
    return v < 0 ? 0 : (v > NT_ - 1 ? NT_ - 1 : v);
}

__global__ __launch_bounds__(64) void detect_k(const unsigned int* __restrict__ px,
                                               const unsigned int* __restrict__ pm,
                                               const unsigned int* __restrict__ pt,
                                               int* __restrict__ flags)
{
    const int t = threadIdx.x;
    int hit = 0;
    for (int i = t; i < 4096; i += 64) {
        unsigned e = (px[i] >> 7) & 0xFFu;
        hit += (e >= 110 && e <= 132) ? 1 : 0;
    }
    for (int s = 1; s < 64; s <<= 1) hit += __shfl_xor(hit, s);

    unsigned big = 0, lo3f = 0, hi3f = 0;
    for (int i = t; i < 1024; i += 64) {
        unsigned wv = pm[i];
        big  |= (wv > 1u) ? 1u : 0u;
        lo3f |= ((wv & 0xFFFFu) == 0x3F80u) ? 1u : 0u;
        hi3f |= ((wv >> 16) == 0x3F80u) ? 1u : 0u;
    }
    unsigned long long aBig = __ballot(big != 0), aLo = __ballot(lo3f != 0), aHi = __ballot(hi3f != 0);

    unsigned tbig = 0, oddnz = 0;
    for (int i = t; i < 512; i += 64) {
        unsigned we = pt[2 * i], wo = pt[2 * i + 1];
        tbig  |= (we > 0xFFFFu || wo > 0xFFFFu) ? 1u : 0u;
        oddnz |= (wo != 0u) ? 1u : 0u;
    }
    unsigned long long aTb = __ballot(tbig != 0), aOdd = __ballot(oddnz != 0);

    if (t == 0) {
        flags[1] = (hit > 2048) ? 1 : 0;
        flags[0] = aLo ? 2 : (aHi ? 3 : (aBig ? 1 : 0));
        flags[2] = aTb ? 2 : (!aOdd ? 1 : 0);
    }
}

// ---------------- weight transpose prep ----------------
template<int BF> __device__ __forceinline__ void wt_prep_body(
    const void* w1, const void* w2, const void* sw2,
    const void* proj, const void* gw1, __hip_bfloat16* wt)
{
    const int idx = blockIdx.x * 256 + threadIdx.x;
    const int stride = gridDim.x * 256;
    for (int i = idx; i < 128 * 192; i += stride) {
        int n = i / 192, k = i - n * 192;
        wt[n * 192 + k] = __float2bfloat16(ldf<BF>(w1, k * 128 + n));
    }
    __hip_bfloat16* w2c = wt + 24576;
    for (int i = idx; i < 128 * 256; i += stride) {
        int n = i >> 8, k = i & 255;
        float v = (k < 128) ? ldf<BF>(w2, k * 128 + n) : ldf<BF>(sw2, (k - 128) * 128 + n);
        w2c[n * 256 + k] = __float2bfloat16(v);
    }
    __hip_bfloat16* pjt = wt + 57344;
    for (int i = idx; i < 128 * 128; i += stride) {
        int n = i >> 7, k = i & 127;
        pjt[n * 128 + k] = __float2bfloat16(ldf<BF>(proj, k * 128 + n));
    }
    __hip_bfloat16* g1t = wt + 73728;
    for (int i = idx; i < 128 * 128; i += stride) {
        int n = i >> 7, k = i & 127;
        g1t[n * 128 + k] = __float2bfloat16(ldf<BF>(gw1, k * 128 + n));
    }
}

__global__ __launch_bounds__(256) void wt_prep_k(
    const void* w1, const void* w2, const void* sw2,
    const void* proj, const void* gw1, __hip_bfloat16* wt, const int* flags)
{
    if (flags[1]) wt_prep_body<1>(w1, w2, sw2, proj, gw1, wt);
    else          wt_prep_body<0>(w1, w2, sw2, proj, gw1, wt);
}

// ---------------- encode L ----------------
#define RL 8
template<int BF> __device__ __forceinline__ void enc_l_body(
    const void* l_x, const void* l_typ, int tm,
    const void* w1, const void* b1, const void* w2, const void* b2,
    const void* lng, const void* lnb, const void* emb, const void* proj,
    const void* dustv, __hip_bfloat16* hLb, float* dust)
{
    __shared__ __align__(16) float X[RL * 8];
    __shared__ __align__(16) float H[RL][D_];
    __shared__ __align__(16) float Y[RL][D_];
    __shared__ float mus[RL], rss[RL];
    const int o = threadIdx.x;
    const int base = blockIdx.x * RL;

    if (o < RL * 8) X[o] = ldf<BF>(l_x, base * 8 + o);
    __syncthreads();

    float acc[RL];
    const float b1o = ldf<BF>(b1, o);
#pragma unroll
    for (int r = 0; r < RL; r++) acc[r] = b1o;
#pragma unroll
    for (int i = 0; i < 8; i += 4) {
        float wa = ldf<BF>(w1, (i + 0) * D_ + o), wb = ldf<BF>(w1, (i + 1) * D_ + o);
        float wc = ldf<BF>(w1, (i + 2) * D_ + o), wd = ldf<BF>(w1, (i + 3) * D_ + o);
#pragma unroll
        for (int r = 0; r < RL; r++) {
            const float4 x4 = *(const float4*)&X[r * 8 + i];
            acc[r] = fmaf(x4.x, wa, fmaf(x4.y, wb, fmaf(x4.z, wc, fmaf(x4.w, wd, acc[r]))));
        }
    }
#pragma unroll
    for (int r = 0; r < RL; r++) H[r][o] = gelu_(acc[r]);
    __syncthreads();

#pragma unroll
    for (int r = 0; r < RL; r++) {
        int tt = typf(l_typ, tm, base + r);
        acc[r] = ldf<BF>(b2, o) + ldf<BF>(emb, tt * D_ + o);
    }
    for (int i = 0; i < D_; i += 4) {
        float wa = ldf<BF>(w2, (i + 0) * D_ + o), wb = ldf<BF>(w2, (i + 1) * D_ + o);
        float wc = ldf<BF>(w2, (i + 2) * D_ + o), wd = ldf<BF>(w2, (i + 3) * D_ + o);
#pragma unroll
        for (int r = 0; r < RL; r++) {
            const float4 h4 = *(const float4*)&H[r][i];
            acc[r] = fmaf(h4.x, wa, fmaf(h4.y, wb, fmaf(h4.z, wc, fmaf(h4.w, wd, acc[r]))));
        }
    }
#pragma unroll
    for (int r = 0; r < RL; r++) Y[r][o] = acc[r];
    __syncthreads();

    {
        const int r = o >> 4, j = o & 15;
        float s = 0.f;
#pragma unroll
        for (int i = 0; i < 8; i++) s += Y[r][j * 8 + i];
        s += __shfl_xor(s, 1); s += __shfl_xor(s, 2); s += __shfl_xor(s, 4); s += __shfl_xor(s, 8);
        const float mu = s * (1.f / 128.f);
        float v = 0.f;
#pragma unroll
        for (int i = 0; i < 8; i++) { float d = Y[r][j * 8 + i] - mu; v = fmaf(d, d, v); }
        v += __shfl_xor(v, 1); v += __shfl_xor(v, 2); v += __shfl_xor(v, 4); v += __shfl_xor(v, 8);
        if (j == 0) { mus[r] = mu; rss[r] = rsqrtf(v * (1.f / 128.f) + 1e-5f); }
    }
    __syncthreads();
    {
        const float g = ldf<BF>(lng, o), bl = ldf<BF>(lnb, o);
#pragma unroll
        for (int r = 0; r < RL; r++) Y[r][o] = fmaf((Y[r][o] - mus[r]) * rss[r], g, bl);
    }
    __syncthreads();

#pragma unroll
    for (int r = 0; r < RL; r++) acc[r] = 0.f;
    for (int i = 0; i < D_; i += 4) {
        float wa = ldf<BF>(proj, (i + 0) * D_ + o), wb = ldf<BF>(proj, (i + 1) * D_ + o);
        float wc = ldf<BF>(proj, (i + 2) * D_ + o), wd = ldf<BF>(proj, (i + 3) * D_ + o);
#pragma unroll
        for (int r = 0; r < RL; r++) {
            const float4 y4 = *(const float4*)&Y[r][i];
            acc[r] = fmaf(y4.x, wa, fmaf(y4.y, wb, fmaf(y4.z, wc, fmaf(y4.w, wd, acc[r]))));
        }
    }
    const float dvo = ldf<BF>(dustv, o);
#pragma unroll
    for (int r = 0; r < RL; r++) {
        hLb[(size_t)(base + r) * D_ + o] = __float2bfloat16(acc[r]);
        H[r][o] = acc[r] * dvo;
    }
    __syncthreads();
    {
        const int r = o >> 4, j = o & 15;
        float s = 0.f;
#pragma unroll
        for (int i = 0; i < 8; i++) s += H[r][j * 8 + i];
        s += __shfl_xor(s, 1); s += __shfl_xor(s, 2); s += __shfl_xor(s, 4); s += __shfl_xor(s, 8);
        if (j == 0) dust[base + r] = s * SCALE_;
    }
}

__global__ __launch_bounds__(128) void enc_l_k(
    const void* l_x, const void* l_typ,
    const void* w1, const void* b1, const void* w2, const void* b2,
    const void* lng, const void* lnb, const void* emb, const void* proj,
    const void* dustv, __hip_bfloat16* hLb, float* dust, const int* flags)
{
    const int tm = flags[2];
    if (flags[1]) enc_l_body<1>(l_x, l_typ, tm, w1, b1, w2, b2, lng, lnb, emb, proj, dustv, hLb, dust);
    else          enc_l_body<0>(l_x, l_typ, tm, w1, b1, w2, b2, lng, lnb, emb, proj, dustv, hLb, dust);
}

// ---------------- encode P (MFMA, 64 rows/block, 256 thr, R11 shape) ----------------
// 4 waves; wave w owns cols 32w..32w+31 (2 n-tiles); M-tiles mt=0..3.
// Lane (m,g): D rows mt*16+g*4+j, cols c0=32w+m, c1=32w+16+m.
#define XS 264
#define ROWS 64
#define ENC_P_SMEM 36608
template<int BF> __device__ __forceinline__ void enc_p_body(
    unsigned short* X, float* red1, float* red2, float* pm_s, float* sc_s, int* tt_s,
    const void* p_x, const void* p_typ, int tm,
    const void* p_score, const void* p_rad,
    const void* b1, const void* b2, const void* sb2,
    const void* sw1, const void* sb1,
    const void* lng, const void* lnb, const void* emb,
    const void* gb1, const void* gw2, const void* gb2,
    const unsigned short* wt, const void* p_mask, int mm,
    void* out, __hip_bfloat16* hPb, float* ppart, float* pcnt)
{
    const int t = threadIdx.x;
    const int o = t & 127, rh = t >> 7;
    const int lane = t & 63, w = t >> 6;
    const int m = lane & 15, g = lane >> 4;
    const int b = blockIdx.x >> 4, tile = blockIdx.x & 15;
    const int base = b * P_ + tile * ROWS;
    const int c0 = 32 * w + m, c1 = 32 * w + 16 + m;
    __hip_bfloat16* Xb = (__hip_bfloat16*)X;

    // stage p_x tile
    if constexpr (BF) {
        const unsigned short* src = (const unsigned short*)p_x + (size_t)base * 192;
#pragma unroll
        for (int i = t * 8; i < ROWS * 192; i += 256 * 8) {
            const int r = i / 192, k = i - r * 192;
            *(bh8*)(X + r * XS + k) = *(const bh8*)(src + i);
        }
    } else {
        for (int i = t; i < ROWS * 192; i += 256) {
            int r = i / 192, k = i - r * 192;
            Xb[r * XS + k] = __float2bfloat16(((const float*)p_x)[(size_t)base * 192 + i]);
        }
    }
    if (t < ROWS) {
        pm_s[t] = maskf(p_mask, mm, base + t);
        sc_s[t] = ldf<BF>(p_score, base + t);
        tt_s[t] = typf(p_typ, tm, base + t);
    }
    __syncthreads();

    // GEMM1: X[64x192] @ w1 (ks-outer)
    fx4 A1[4][2];
#pragma unroll
    for (int mt = 0; mt < 4; mt++) { A1[mt][0] = fx4{0,0,0,0}; A1[mt][1] = fx4{0,0,0,0}; }
    {
        const unsigned short* q0 = wt + ((2 * w + 0) * 16 + m) * 192 + g * 8;
        const unsigned short* q1 = wt + ((2 * w + 1) * 16 + m) * 192 + g * 8;
#pragma unroll
        for (int ks = 0; ks < 6; ks++) {
            bh8 f0 = *(const bh8*)(q0 + ks * 32);
            bh8 f1 = *(const bh8*)(q1 + ks * 32);
#pragma unroll
            for (int mt = 0; mt < 4; mt++) {
                bh8 a = *(const bh8*)(X + (mt * 16 + m) * XS + g * 8 + ks * 32);
                A1[mt][0] = __builtin_amdgcn_mfma_f32_16x16x32_bf16(a, f0, A1[mt][0], 0, 0, 0);
                A1[mt][1] = __builtin_amdgcn_mfma_f32_16x16x32_bf16(a, f1, A1[mt][1], 0, 0, 0);
            }
        }
    }
    __syncthreads();

    // ep1: h1 = gelu(D + b1) -> X[:,0:128]; hs -> X[:,128:256]
    {
        const float bb0 = ldf<BF>(b1, c0), bb1 = ldf<BF>(b1, c1);
#pragma unroll
        for (int mt = 0; mt < 4; mt++)
#pragma unroll
            for (int j = 0; j < 4; j++) {
                const int row = mt * 16 + g * 4 + j;
                Xb[row * XS + c0] = __float2bfloat16(gelu_(A1[mt][0][j] + bb0));
                Xb[row * XS + c1] = __float2bfloat16(gelu_(A1[mt][1][j] + bb1));
            }
    }
    {
        const float a1v = ldf<BF>(sw1, o), a0v = ldf<BF>(sb1, o);
#pragma unroll
        for (int r = 0; r < 32; r++) {
            const int row = rh * 32 + r;
            Xb[row * XS + 128 + o] = __float2bfloat16(gelu_(fmaf(sc_s[row], a1v, a0v)));
        }
    }
    __syncthreads();

    // GEMM2: [h1|hs][64x256] @ w2c
    fx4 A2[4][2];
#pragma unroll
    for (int mt = 0; mt < 4; mt++) { A2[mt][0] = fx4{0,0,0,0}; A2[mt][1] = fx4{0,0,0,0}; }
    {
        const unsigned short* w2cT = wt + 24576;
        const unsigned short* q0 = w2cT + ((2 * w + 0) * 16 + m) * 256 + g * 8;
        const unsigned short* q1 = w2cT + ((2 * w + 1) * 16 + m) * 256 + g * 8;
#pragma unroll
        for (int ks = 0; ks < 8; ks++) {
            bh8 f0 = *(const bh8*)(q0 + ks * 32);
            bh8 f1 = *(const bh8*)(q1 + ks * 32);
#pragma unroll
            for (int mt = 0; mt < 4; mt++) {
                bh8 a = *(const bh8*)(X + (mt * 16 + m) * XS + g * 8 + ks * 32);
                A2[mt][0] = __builtin_amdgcn_mfma_f32_16x16x32_bf16(a, f0, A2[mt][0], 0, 0, 0);
                A2[mt][1] = __builtin_amdgcn_mfma_f32_16x16x32_bf16(a, f1, A2[mt][1], 0, 0, 0);
            }
        }
    }
    // ep2: h2 = D + b2 + sb2 + emb[typ]
    {
        const float bc0 = ldf<BF>(b2, c0) + ldf<BF>(sb2, c0);
        const float bc1 = ldf<BF>(b2, c1) + ldf<BF>(sb2, c1);
#pragma unroll
        for (int mt = 0; mt < 4; mt++)
#pragma unroll
            for (int j = 0; j < 4; j++) {
                const int row = mt * 16 + g * 4 + j;
                const int tt = tt_s[row];
                A2[mt][0][j] += bc0 + ldf<BF>(emb, tt * D_ + c0);
                A2[mt][1][j] += bc1 + ldf<BF>(emb, tt * D_ + c1);
            }
    }
    // single-pass LN partials: sum + sumsq in ONE reduction round
#pragma unroll
    for (int mt = 0; mt < 4; mt++)
#pragma unroll
        for (int j = 0; j < 4; j++) {
            const int row = mt * 16 + g * 4 + j;
            float s = A2[mt][0][j] + A2[mt][1][j];
            float q = fmaf(A2[mt][0][j], A2[mt][0][j], A2[mt][1][j] * A2[mt][1][j]);
            s += __shfl_xor(s, 1); s += __shfl_xor(s, 2); s += __shfl_xor(s, 4); s += __shfl_xor(s, 8);
            q += __shfl_xor(q, 1); q += __shfl_xor(q, 2); q += __shfl_xor(q, 4); q += __shfl_xor(q, 8);
            if (m == 0) { red1[row * 4 + w] = s; red2[row * 4 + w] = q; }
        }
    __syncthreads();
    // LN apply -> X bf16
    {
        const float gc0 = ldf<BF>(lng, c0), bl0 = ldf<BF>(lnb, c0);
        const float gc1 = ldf<BF>(lng, c1), bl1 = ldf<BF>(lnb, c1);
#pragma unroll
        for (int mt = 0; mt < 4; mt++)
#pragma unroll
            for (int j = 0; j < 4; j++) {
                const int row = mt * 16 + g * 4 + j;
                float S = (red1[row * 4 + 0] + red1[row * 4 + 1]) + (red1[row * 4 + 2] + red1[row * 4 + 3]);
                float Q = (red2[row * 4 + 0] + red2[row * 4 + 1]) + (red2[row * 4 + 2] + red2[row * 4 + 3]);
                float mu = S * (1.f / 128.f);
                float var = fmaf(Q, 1.f / 128.f, -mu * mu);
                float rs = rsqrtf(var + 1e-5f);
                float y0 = fmaf((A2[mt][0][j] - mu) * rs, gc0, bl0);
                float y1 = fmaf((A2[mt][1][j] - mu) * rs, gc1, bl1);
                Xb[row * XS + c0] = __float2bfloat16(y0);
                Xb[row * XS + c1] = __float2bfloat16(y1);
            }
    }
    __syncthreads();

    // GEMM3: hp = y[64x128] @ proj
    fx4 A3[4][2];
#pragma unroll
    for (int mt = 0; mt < 4; mt++) { A3[mt][0] = fx4{0,0,0,0}; A3[mt][1] = fx4{0,0,0,0}; }
    {
        const unsigned short* pjT = wt + 57344;
        const unsigned short* q0 = pjT + ((2 * w + 0) * 16 + m) * 128 + g * 8;
        const unsigned short* q1 = pjT + ((2 * w + 1) * 16 + m) * 128 + g * 8;
#pragma unroll
        for (int ks = 0; ks < 4; ks++) {
            bh8 f0 = *(const bh8*)(q0 + ks * 32);
            bh8 f1 = *(const bh8*)(q1 + ks * 32);
#pragma unroll
            for (int mt = 0; mt < 4; mt++) {
                bh8 a = *(const bh8*)(X + (mt * 16 + m) * XS + g * 8 + ks * 32);
                A3[mt][0] = __builtin_amdgcn_mfma_f32_16x16x32_bf16(a, f0, A3[mt][0], 0, 0, 0);
                A3[mt][1] = __builtin_amdgcn_mfma_f32_16x16x32_bf16(a, f1, A3[mt][1], 0, 0, 0);
            }
        }
    }
    __syncthreads();

    // ep3: hPb store + X <- hp bf16 + pool partials
    {
#pragma unroll
        for (int mt = 0; mt < 4; mt++)
#pragma unroll
            for (int j = 0; j < 4; j++) {
                const int row = mt * 16 + g * 4 + j;
                __hip_bfloat16 h0 = __float2bfloat16(A3[mt][0][j]);
                __hip_bfloat16 h1 = __float2bfloat16(A3[mt][1][j]);
                hPb[(size_t)(base + row) * D_ + c0] = h0;
                hPb[(size_t)(base + row) * D_ + c1] = h1;
                Xb[row * XS + c0] = h0;
                Xb[row * XS + c1] = h1;
            }
        float ps0 = 0.f, ps1 = 0.f;
#pragma unroll
        for (int mt = 0; mt < 4; mt++)
#pragma unroll
            for (int j = 0; j < 4; j++) {
                const int row = mt * 16 + g * 4 + j;
                ps0 = fmaf(A3[mt][0][j], pm_s[row], ps0);
                ps1 = fmaf(A3[mt][1][j], pm_s[row], ps1);
            }
        ps0 += __shfl_xor(ps0, 16); ps0 += __shfl_xor(ps0, 32);
        ps1 += __shfl_xor(ps1, 16); ps1 += __shfl_xor(ps1, 32);
        if (g == 0) {
            ppart[(size_t)blockIdx.x * D_ + c0] = ps0;
            ppart[(size_t)blockIdx.x * D_ + c1] = ps1;
        }
        if (t == 0) {
            float c = 0.f;
#pragma unroll
            for (int r = 0; r < ROWS; r++) c += pm_s[r];
            pcnt[blockIdx.x] = c;
        }
    }
    __syncthreads();

    // GEMM4: g1raw = hp[64x128] @ gw1
    fx4 A4[4][2];
#pragma unroll
    for (int mt = 0; mt < 4; mt++) { A4[mt][0] = fx4{0,0,0,0}; A4[mt][1] = fx4{0,0,0,0}; }
    {
        const unsigned short* g1T = wt + 73728;
        const unsigned short* q0 = g1T + ((2 * w + 0) * 16 + m) * 128 + g * 8;
        const unsigned short* q1 = g1T + ((2 * w + 1) * 16 + m) * 128 + g * 8;
#pragma unroll
        for (int ks = 0; ks < 4; ks++) {
            bh8 f0 = *(const bh8*)(q0 + ks * 32);
            bh8 f1 = *(const bh8*)(q1 + ks * 32);
#pragma unroll
            for (int mt = 0; mt < 4; mt++) {
                bh8 a = *(const bh8*)(X + (mt * 16 + m) * XS + g * 8 + ks * 32);
                A4[mt][0] = __builtin_amdgcn_mfma_f32_16x16x32_bf16(a, f0, A4[mt][0], 0, 0, 0);
                A4[mt][1] = __builtin_amdgcn_mfma_f32_16x16x32_bf16(a, f1, A4[mt][1], 0, 0, 0);
            }
        }
    }
    // ep4: g1 = gelu(D+gb1); sigma dot partials
    {
        const float gb0 = ldf<BF>(gb1, c0), gb1v = ldf<BF>(gb1, c1);
        const float w20 = ldf<BF>(gw2, c0), w21 = ldf<BF>(gw2, c1);
#pragma unroll
        for (int mt = 0; mt < 4; mt++)
#pragma unroll
            for (int j = 0; j < 4; j++) {
                const int row = mt * 16 + g * 4 + j;
                float g0 = gelu_(A4[mt][0][j] + gb0);
                float g1v = gelu_(A4[mt][1][j] + gb1v);
                float p = fmaf(g0, w20, g1v * w21);
                p += __shfl_xor(p, 1); p += __shfl_xor(p, 2); p += __shfl_xor(p, 4); p += __shfl_xor(p, 8);
                if (m == 0) red1[row * 4 + w] = p;
            }
    }
    __syncthreads();
    if (t < ROWS) {
        float s = (red1[t * 4 + 0] + red1[t * 4 + 1]) + (red1[t * 4 + 2] + red1[t * 4 + 3]);
        float v = s + ldf<BF>(gb2, 0);
        float sp = fmaxf(v, 0.f) + log1pf(expf(-fabsf(v)));
        stf<BF>(out, (size_t)OUT_SIG + base + t, sp + 1e-3f + fmaxf(ldf<BF>(p_rad, base + t), 0.f));
    }
}

__global__ __launch_bounds__(256) void enc_p_k(
    const void* p_x, const void* p_typ, const void* p_score, const void* p_rad,
    const void* b1, const void* b2, const void* sb2,
    const void* sw1, const void* sb1,
    const void* lng, const void* lnb, const void* emb,
    const void* gb1, const void* gw2, const void* gb2,
    const unsigned short* wt, const void* p_mask, const int* flags,
    void* out, __hip_bfloat16* hPb, float* ppart, float* pcnt)
{
    extern __shared__ __align__(16) char smem[];
    unsigned short* X = (unsigned short*)smem;          // 64*264*2 = 33792 B
    float* red1 = (float*)(smem + 33792);               // 1024 B
    float* red2 = (float*)(smem + 34816);               // 1024 B
    float* pm_s = (float*)(smem + 35840);               // 256 B
    float* sc_s = (float*)(smem + 36096);               // 256 B
    int*   tt_s = (int*)(smem + 36352);                 // 256 B
    const int tm = flags[2], mm = flags[0];
    if (flags[1]) enc_p_body<1>(X, red1, red2, pm_s, sc_s, tt_s,
                                p_x, p_typ, tm, p_score, p_rad, b1, b2, sb2, sw1, sb1,
                                lng, lnb, emb, gb1, gw2, gb2, wt, p_mask, mm,
                                out, hPb, ppart, pcnt);
    else          enc_p_body<0>(X, red1, red2, pm_s, sc_s, tt_s,
                                p_x, p_typ, tm, p_score, p_rad, b1, b2, sb2, sw1, sb1,
                                lng, lnb, emb, gb1, gw2, gb2, wt, p_mask, mm,
                                out, hPb, ppart, pcnt);
}

// ---------------- logits (MFMA) + fused softmax + sharp/ent ----------------
template<int BF> __device__ __forceinline__ void logits_sm_body(
    const unsigned short* hLb, const unsigned short* hPb, const float* dust,
    const void* l_mask, const void* p_mask, int mm,
    void* out, float* sharp_parts, float* ent_parts)
{
    __shared__ float pm_s[1024];
    __shared__ float lm_s[16], dv_s[16];
    __shared__ float redA[64], redB[64], redC[64], redD[64], redM[16], redL[16];
    const int t = threadIdx.x;
    const int lane = t & 63, w = t >> 6;
    const int m = lane & 15, g = lane >> 4;
    const int b = blockIdx.x & 127, l0 = (blockIdx.x >> 7) * 16;

    for (int i = t; i < 1024; i += 256) pm_s[i] = maskf(p_mask, mm, b * P_ + i);
    if (t < 16) {
        lm_s[t] = maskf(l_mask, mm, b * L_ + l0 + t);
        dv_s[t] = dust[b * L_ + l0 + t];
    }
    __syncthreads();

    bh8 af[4];
    {
        const unsigned short* ha = hLb + ((size_t)(b * L_ + l0 + m)) * D_ + g * 8;
#pragma unroll
        for (int ks = 0; ks < 4; ks++) af[ks] = *(const bh8*)(ha + ks * 32);
    }
    const unsigned short* hpb = hPb + ((size_t)(b * P_ + w * 256)) * D_;

    fx4 acc[16];
#pragma unroll
    for (int nt = 0; nt < 16; nt++) {
        fx4 c = {0.f, 0.f, 0.f, 0.f};
        const unsigned short* hr = hpb + (nt * 16 + m) * D_ + g * 8;
#pragma unroll
        for (int ks = 0; ks < 4; ks++) {
            bh8 bfr = *(const bh8*)(hr + ks * 32);
            c = __builtin_amdgcn_mfma_f32_16x16x32_bf16(af[ks], bfr, c, 0, 0, 0);
        }
        acc[nt] = c;
    }

    float rmax[4] = {NEGF, NEGF, NEGF, NEGF};
#pragma unroll
    for (int nt = 0; nt < 16; nt++) {
        const float pv = pm_s[w * 256 + nt * 16 + m];
#pragma unroll
        for (int j = 0; j < 4; j++) {
            const bool ok = (lm_s[g * 4 + j] != 0.f) && (pv != 0.f);
            float v = ok ? acc[nt][j] * SCALE_ : NEGF;
            acc[nt][j] = v;
            rmax[j] = fmaxf(rmax[j], v);
        }
    }
#pragma unroll
    for (int j = 0; j < 4; j++) {
        rmax[j] = fmaxf(rmax[j], __shfl_xor(rmax[j], 1));
        rmax[j] = fmaxf(rmax[j], __shfl_xor(rmax[j], 2));
        rmax[j] = fmaxf(rmax[j], __shfl_xor(rmax[j], 4));
        rmax[j] = fmaxf(rmax[j], __shfl_xor(rmax[j], 8));
    }
    if (m == 0) {
#pragma unroll
        for (int j = 0; j < 4; j++) redA[(g * 4 + j) * 4 + w] = rmax[j];
    }
    __syncthreads();
    float mrow[4], lse[4];
#pragma unroll
    for (int j = 0; j < 4; j++) {
        const int r = g * 4 + j;
        float mm4 = fmaxf(fmaxf(redA[r * 4 + 0], redA[r * 4 + 1]), fmaxf(redA[r * 4 + 2], redA[r * 4 + 3]));
        float dvr = (lm_s[r] != 0.f) ? dv_s[r] : NEGF;
        mrow[j] = fmaxf(mm4, dvr);
    }
    float se[4] = {0.f, 0.f, 0.f, 0.f};
#pragma unroll
    for (int nt = 0; nt < 16; nt++) {
#pragma unroll
        for (int j = 0; j < 4; j++) se[j] += __expf(acc[nt][j] - mrow[j]);
    }
#pragma unroll
    for (int j = 0; j < 4; j++) {
        se[j] += __shfl_xor(se[j], 1); se[j] += __shfl_xor(se[j], 2);
        se[j] += __shfl_xor(se[j], 4); se[j] += __shfl_xor(se[j], 8);
    }
    if (m == 0) {
#pragma unroll
        for (int j = 0; j < 4; j++) redB[(g * 4 + j) * 4 + w] = se[j];
    }
    __syncthreads();
#pragma unroll
    for (int j = 0; j < 4; j++) {
        const int r = g * 4 + j;
        float dvr = (lm_s[r] != 0.f) ? dv_s[r] : NEGF;
        float s = (redB[r * 4 + 0] + redB[r * 4 + 1]) + (redB[r * 4 + 2] + redB[r * 4 + 3]);
        s += __expf(dvr - mrow[j]);
        lse[j] = __logf(s);
    }
    if (w == 0 && m == 0) {
#pragma unroll
        for (int j = 0; j < 4; j++) { redM[g * 4 + j] = mrow[j]; redL[g * 4 + j] = lse[j]; }
    }
    float mw[4] = {0.f, 0.f, 0.f, 0.f}, es[4] = {0.f, 0.f, 0.f, 0.f};
#pragma unroll
    for (int nt = 0; nt < 16; nt++) {
        const float pv = pm_s[w * 256 + nt * 16 + m];
#pragma unroll
        for (int j = 0; j < 4; j++) {
            float lw = acc[nt][j] - mrow[j] - lse[j];
            stf<BF>(out, (size_t)(b * L_ + l0 + g * 4 + j) * (P_ + 1) + w * 256 + nt * 16 + m, lw);
            float lwc = fmaxf(lw, -CLAMPV);
            float wm = __expf(lwc) * pv;
            mw[j] = fmaxf(mw[j], wm);
            if (wm > 0.f) es[j] = fmaf(-wm, lwc, es[j]);
        }
    }
#pragma unroll
    for (int j = 0; j < 4; j++) {
        mw[j] = fmaxf(mw[j], __shfl_xor(mw[j], 1));
        mw[j] = fmaxf(mw[j], __shfl_xor(mw[j], 2));
        mw[j] = fmaxf(mw[j], __shfl_xor(mw[j], 4));
        mw[j] = fmaxf(mw[j], __shfl_xor(mw[j], 8));
        es[j] += __shfl_xor(es[j], 1); es[j] += __shfl_xor(es[j], 2);
        es[j] += __shfl_xor(es[j], 4); es[j] += __shfl_xor(es[j], 8);
    }
    if (m == 0) {
#pragma unroll
        for (int j = 0; j < 4; j++) {
            redC[(g * 4 + j) * 4 + w] = mw[j];
            redD[(g * 4 + j) * 4 + w] = es[j];
        }
    }
    __syncthreads();
    if (t < 16) {
        float dvr = (lm_s[t] != 0.f) ? dv_s[t] : NEGF;
        stf<BF>(out, (size_t)(b * L_ + l0 + t) * (P_ + 1) + P_, dvr - redM[t] - redL[t]);
    }
    if (t == 0) {
        float sp = 0.f, en = 0.f;
        for (int r = 0; r < 16; r++) {
            float dvr = (lm_s[r] != 0.f) ? dv_s[r] : NEGF;
            float lwd = fmaxf(dvr - redM[r] - redL[r], -CLAMPV);
            float wd = __expf(lwd);
            float mwr = fmaxf(fmaxf(redC[r * 4 + 0], redC[r * 4 + 1]), fmaxf(redC[r * 4 + 2], redC[r * 4 + 3]));
            mwr = fmaxf(mwr, wd);
            float esr = (redD[r * 4 + 0] + redD[r * 4 + 1]) + (redD[r * 4 + 2] + redD[r * 4 + 3]);
            if (wd > 0.f) esr = fmaf(-wd, lwd, esr);
            sp = fmaf(mwr, lm_s[r], sp);
            en = fmaf(esr, lm_s[r], en);
        }
        sharp_parts[blockIdx.x] = sp;
        ent_parts[blockIdx.x] = en;
    }
}

__global__ __launch_bounds__(256) void logits_sm_k(
    const unsigned short* hLb, const unsigned short* hPb, const float* dust,
    const void* l_mask, const void* p_mask, const int* flags,
    void* out, float* sharp_parts, float* ent_parts)
{
    const int mm = flags[0];
    if (flags[1]) logits_sm_body<1>(hLb, hPb, dust, l_mask, p_mask, mm, out, sharp_parts, ent_parts);
    else          logits_sm_body<0>(hLb, hPb, dust, l_mask, p_mask, mm, out, sharp_parts, ent_parts);
}

// ---------------- epilogue: pool_l + pool_p + finalize ----------------
template<int BF> __device__ __forceinline__ void epilogue_body(
    const unsigned short* hLb, const void* l_mask, int mm,
    const void* retr_l, const void* retr_p,
    const float* ppart, const float* pcnt,
    const float* sharp_parts, const float* ent_parts, void* out)
{
    __shared__ float lmv[L_];
    __shared__ __align__(16) float lg[D_];
    __shared__ __align__(16) float pgs[D_];
    __shared__ float red[4];
    const int o = threadIdx.x, b = blockIdx.x;
    lmv[o] = maskf(l_mask, mm, b * L_ + o);
    __syncthreads();
    float cnt = 0.f;
    for (int l = 0; l < L_; l++) cnt += lmv[l];
    {
        float s0 = 0, s1 = 0, s2 = 0, s3 = 0;
        const unsigned short* hb = hLb + (size_t)b * L_ * D_;
        for (int l = 0; l < L_; l += 4) {
            s0 = fmaf(bf2f(hb[(l + 0) * D_ + o]), lmv[l + 0], s0);
            s1 = fmaf(bf2f(hb[(l + 1) * D_ + o]), lmv[l + 1], s1);
            s2 = fmaf(bf2f(hb[(l + 2) * D_ + o]), lmv[l + 2], s2);
            s3 = fmaf(bf2f(hb[(l + 3) * D_ + o]), lmv[l + 3], s3);
        }
        lg[o] = ((s0 + s1) + (s2 + s3)) / fmaxf(cnt, 1.f);
    }
    {
        float s = 0.f, c = 0.f;
        for (int k = 0; k < 16; k++) s += ppart[(size_t)(b * 16 + k) * D_ + o];
        for (int k = 0; k < 16; k++) c += pcnt[b * 16 + k];
        pgs[o] = s / fmaxf(c, 1.f);
    }
    __syncthreads();
    float rL = 0.f, rP = 0.f;
    for (int i = 0; i < D_; i += 4) {
        const float4 g4 = *(const float4*)&lg[i];
        rL = fmaf(g4.x, ldf<BF>(retr_l, (i + 0) * D_ + o), rL);
        rL = fmaf(g4.y, ldf<BF>(retr_l, (i + 1) * D_ + o), rL);
        rL = fmaf(g4.z, ldf<BF>(retr_l, (i + 2) * D_ + o), rL);
        rL = fmaf(g4.w, ldf<BF>(retr_l, (i + 3) * D_ + o), rL);
        const float4 p4 = *(const float4*)&pgs[i];
        rP = fmaf(p4.x, ldf<BF>(retr_p, (i + 0) * D_ + o), rP);
        rP = fmaf(p4.y, ldf<BF>(retr_p, (i + 1) * D_ + o), rP);
        rP = fmaf(p4.z, ldf<BF>(retr_p, (i + 2) * D_ + o), rP);
        rP = fmaf(p4.w, ldf<BF>(retr_p, (i + 3) * D_ + o), rP);
    }
    float nL = rL * rL, nP = rP * rP;
    nL += __shfl_xor(nL, 1); nL += __shfl_xor(nL, 2); nL += __shfl_xor(nL, 4);
    nL += __shfl_xor(nL, 8); nL += __shfl_xor(nL, 16); nL += __shfl_xor(nL, 32);
    nP += __shfl_xor(nP, 1); nP += __shfl_xor(nP, 2); nP += __shfl_xor(nP, 4);
    nP += __shfl_xor(nP, 8); nP += __shfl_xor(nP, 16); nP += __shfl_xor(nP, 32);
    if ((o & 63) == 0) { red[o >> 6] = nL; red[2 + (o >> 6)] = nP; }
    __syncthreads();
    {
        float nrmL = fmaxf(sqrtf(red[0] + red[1]), 1e-12f);
        float nrmP = fmaxf(sqrtf(red[2] + red[3]), 1e-12f);
        stf<BF>(out, (size_t)OUT_LZ + b * D_ + o, rL / nrmL);
        stf<BF>(out, (size_t)OUT_PZ + b * D_ + o, rP / nrmP);
    }
    if (o == 0) {
        const float den = fmaxf(cnt, 1.f);
        float sp = 0.f, en = 0.f;
        for (int k = 0; k < 8; k++) { sp += sharp_parts[k * 128 + b]; en += ent_parts[k * 128 + b]; }
        stf<BF>(out, (size_t)OUT_SHARP + b, sp / den);
        stf<BF>(out, (size_t)OUT_NEGENT + b, -(en / den));
    }
}

__global__ __launch_bounds__(128) void epilogue_k(
    const unsigned short* hLb, const void* l_mask, const int* flags,
    const void* retr_l, const void* retr_p,
    const float* ppart, const float* pcnt,
    const float* sharp_parts, const float* ent_parts, void* out)
{
    const int mm = flags[0];
    if (flags[1]) epilogue_body<1>(hLb, l_mask, mm, retr_l, retr_p, ppart, pcnt, sharp_parts, ent_parts, out);
    else          epilogue_body<0>(hLb, l_mask, mm, retr_l, retr_p, ppart, pcnt, sharp_parts, ent_parts, out);
}

extern "C" void kernel_launch(void* const* d_in, const int* in_sizes, int n_in,
                              void* d_out, int out_size, void* d_ws, size_t ws_size,
                              hipStream_t stream)
{
    const void* l_x     = d_in[0];
    const void* l_typ   = d_in[1];
    const void* p_x     = d_in[2];
    const void* p_typ   = d_in[3];
    const void* p_score = d_in[4];
    const void* p_rad   = d_in[5];
    const void* l_mask  = d_in[6];
    const void* p_mask  = d_in[7];
    const void* lt_emb  = d_in[8];
    const void* lx_w1   = d_in[9];
    const void* lx_b1   = d_in[10];
    const void* lx_w2   = d_in[11];
    const void* lx_b2   = d_in[12];
    const void* l_ln_g  = d_in[13];
    const void* l_ln_b  = d_in[14];
    const void* pt_emb  = d_in[15];
    const void* px_w1   = d_in[16];
    const void* px_b1   = d_in[17];
    const void* px_w2   = d_in[18];
    const void* px_b2   = d_in[19];
    const void* ps_w1   = d_in[20];
    const void* ps_b1   = d_in[21];
    const void* ps_w2   = d_in[22];
    const void* ps_b2   = d_in[23];
    const void* p_ln_g  = d_in[24];
    const void* p_ln_b  = d_in[25];
    const void* proj_l  = d_in[26];
    const void* proj_p  = d_in[27];
    const void* dustv   = d_in[28];
    const void* sg_w1   = d_in[29];
    const void* sg_b1   = d_in[30];
    const void* sg_w2   = d_in[31];
    const void* sg_b2   = d_in[32];
    const void* retr_l  = d_in[33];
    const void* retr_p  = d_in[34];

    float* ws     = (float*)d_ws;
    __hip_bfloat16* hLb = (__hip_bfloat16*)(ws + WS_HLB);
    __hip_bfloat16* hPb = (__hip_bfloat16*)(ws + WS_HPB);
    float* dust   = ws + WS_DUST;
    float* sharpp = ws + WS_SHARPP;
    float* entp   = ws + WS_ENTP;
    int*   flags  = (int*)(ws + WS_FLAG);
    __hip_bfloat16* wt = (__hip_bfloat16*)(ws + WS_WT);
    float* ppart  = ws + WS_PPART;
    float* pcnt   = ws + WS_PCNT;

    detect_k<<<1, 64, 0, stream>>>((const unsigned int*)p_x, (const unsigned int*)p_mask,
                                   (const unsigned int*)p_typ, flags);
    wt_prep_k<<<64, 256, 0, stream>>>(px_w1, px_w2, ps_w2, proj_p, sg_w1, wt, flags);
    enc_l_k<<<(B_ * L_) / RL, 128, 0, stream>>>(l_x, l_typ, lx_w1, lx_b1, lx_w2, lx_b2,
                                                l_ln_g, l_ln_b, lt_emb, proj_l, dustv,
                                                hLb, dust, flags);
    enc_p_k<<<B_ * (P_ / ROWS), 256, ENC_P_SMEM, stream>>>(
        p_x, p_typ, p_score, p_rad,
        px_b1, px_b2, ps_b2, ps_w1, ps_b1,
        p_ln_g, p_ln_b, pt_emb,
        sg_b1, sg_w2, sg_b2,
        (const unsigned short*)wt, p_mask, flags,
        d_out, hPb, ppart, pcnt);
    logits_sm_k<<<B_ * 8, 256, 0, stream>>>((const unsigned short*)hLb, (const unsigned short*)hPb,
                                            dust, l_mask, p_mask, flags, d_out, sharpp, entp);
    epilogue_k<<<B_, 128, 0, stream>>>((const unsigned short*)hLb, l_mask, flags,
                                       retr_l, retr_p, ppart, pcnt, sharpp, entp, d_out);
}